// Round 7
// baseline (1847.402 us; speedup 1.0000x reference)
//
#include <hip/hip_runtime.h>
#include <math.h>

#define TT 1024
#define BB 8
#define DD 512
#define HH 8
#define HSZ 64
#define LL 6
#define FF4 2048

typedef __attribute__((ext_vector_type(8))) short short8;
typedef __attribute__((ext_vector_type(4))) float floatx4;
typedef unsigned short ushort_t;
typedef unsigned int uint_t;

__device__ __forceinline__ ushort_t f2bf(float f) {
  uint_t u = __float_as_uint(f);
  u += 0x7fff + ((u >> 16) & 1);  // RNE
  return (ushort_t)(u >> 16);
}
__device__ __forceinline__ float bf2f(ushort_t h) {
  return __uint_as_float(((uint_t)h) << 16);
}

__device__ __forceinline__ void gload16(const void* g, void* l) {
  __builtin_amdgcn_global_load_lds((const __attribute__((address_space(1))) void*)g,
                                   (__attribute__((address_space(3))) void*)l, 16, 0, 0);
}

// XCD swizzle: blocks assigned round-robin to XCDs by id%8; remap so the gx
// column-blocks of one row-block have ids congruent mod 8 (same XCD L2).
__device__ __forceinline__ void xcd_swz(int gx, int& bx, int& by) {
  int id = blockIdx.y * gx + blockIdx.x;
  bx = (id >> 3) % gx;
  by = (id / (8 * gx)) * 8 + (id & 7);
}

// ---------------- embed + positional encoding ----------------
__global__ __launch_bounds__(256) void k_embed(const int* __restrict__ code,
                                               const float* __restrict__ emb,
                                               float* __restrict__ x) {
  int idx = blockIdx.x * 256 + threadIdx.x;  // over B*T*D
  int c = idx & (DD - 1);
  int bt = idx >> 9;
  int t = bt & (TT - 1);
  int f = c >> 4, e = c & 15;
  int vv = code[bt * 32 + f];
  int i = c >> 1;
  float freq = expf((float)(2 * i) * (-9.210340371976184f / 512.f));
  float ang = (float)t * freq;
  float pe = (c & 1) ? cosf(ang) : sinf(ang);
  x[idx] = emb[vv * 16 + e] + pe;
}

// ---------------- layernorm (+ optional fused attention-pool score) ----------------
__global__ __launch_bounds__(256) void k_ln(const float* __restrict__ x,
                                            ushort_t* __restrict__ yB,
                                            float* __restrict__ yF,
                                            const float* __restrict__ g,
                                            const float* __restrict__ b,
                                            const float* __restrict__ aw,
                                            const float* __restrict__ ab,
                                            float* __restrict__ scores) {
  int wave = threadIdx.x >> 6, lane = threadIdx.x & 63;
  int row = blockIdx.x * 4 + wave;
  const float* xr = x + (size_t)row * DD;
  float v[8];
  float s = 0.f;
#pragma unroll
  for (int j = 0; j < 8; ++j) { v[j] = xr[lane + 64 * j]; s += v[j]; }
#pragma unroll
  for (int off = 32; off; off >>= 1) s += __shfl_down(s, off, 64);
  float mean = __shfl(s, 0, 64) * (1.f / DD);
  float qv = 0.f;
#pragma unroll
  for (int j = 0; j < 8; ++j) { float d = v[j] - mean; qv += d * d; }
#pragma unroll
  for (int off = 32; off; off >>= 1) qv += __shfl_down(qv, off, 64);
  float rs = rsqrtf(__shfl(qv, 0, 64) * (1.f / DD) + 1e-5f);
  float sdot = 0.f;
#pragma unroll
  for (int j = 0; j < 8; ++j) {
    int c = lane + 64 * j;
    float val = (v[j] - mean) * rs * g[c] + b[c];
    if (yB) yB[(size_t)row * DD + c] = f2bf(val);
    else    yF[(size_t)row * DD + c] = val;
    if (scores) sdot += val * aw[c];
  }
  if (scores) {
#pragma unroll
    for (int off = 32; off; off >>= 1) sdot += __shfl_down(sdot, off, 64);
    if (lane == 0) scores[row] = sdot + ab[0];
  }
}

// ---------------- fp32 -> bf16 transposed weight prep ----------------
__global__ __launch_bounds__(256) void k_transpose(const float* __restrict__ in,
                                                   ushort_t* __restrict__ out,
                                                   int Nin, long in_ms, int nh,
                                                   long os_l, long os_h, int out_ld) {
  __shared__ float t4[64][65];
  int mz = blockIdx.z;
  const float* ip = in + (size_t)mz * in_ms;
  ushort_t* op = out + (size_t)(mz / nh) * os_l + (size_t)(mz % nh) * os_h;
  int k0 = blockIdx.x * 64, n0 = blockIdx.y * 64;
  int c = threadIdx.x & 63, r0 = threadIdx.x >> 6;
#pragma unroll
  for (int i = 0; i < 16; ++i) {
    int r = r0 * 16 + i;
    t4[r][c] = ip[(size_t)(k0 + r) * Nin + n0 + c];
  }
  __syncthreads();
#pragma unroll
  for (int i = 0; i < 16; ++i) {
    int n = r0 * 16 + i;
    op[(size_t)(n0 + n) * out_ld + k0 + c] = f2bf(t4[c][n]);
  }
}

// ---------------- bf16 MFMA GEMM, 64x128 tile, BK=32, dbuf (6 blocks/CU) ----------------
// Buffer (6144 shorts): A slot(kc,m)=(kc*64+m)*8; B at +2048, slot(kc,n)=(kc*128+n)*8.
// Waves 2x2: wm over 32-row halves, wn over 64-col halves; 8 MFMA/wave/iter.
__global__ __launch_bounds__(256, 6) void k_gemm(const ushort_t* __restrict__ A,
                                                 const ushort_t* __restrict__ Bt,
                                                 const float* __restrict__ resid,
                                                 const float* __restrict__ bias,
                                                 float* __restrict__ outF,
                                                 ushort_t* __restrict__ outB,
                                                 int M, int N, int K, int dogelu) {
  __shared__ short lds[12288];
  const int tid = threadIdx.x;
  const int w = tid >> 6, lane = tid & 63;
  const int quad = lane >> 4, l16 = lane & 15;
  const int wm = w >> 1, wn = w & 1;
  int bx, by;
  xcd_swz(gridDim.x, bx, by);
  const int row0 = by * 64, col0 = bx * 128;
  const short* Ag = (const short*)A + (size_t)(row0 + lane) * K + w * 8;
  const short* Bg = (const short*)Bt + (size_t)(col0 + lane) * K + w * 8;
  floatx4 acc[2][4] = {};
  const int sA = w * 512;
  const int sB = 2048 + w * 1024;
  {
    short* base = &lds[0];
    gload16(Ag, base + sA);
    gload16(Bg, base + sB);
    gload16(Bg + (size_t)64 * K, base + sB + 512);
  }
  const int nk = K >> 5;
  for (int i = 0; i < nk; ++i) {
    __syncthreads();
    if (i + 1 < nk) {
      const int k0 = (i + 1) << 5;
      short* base = &lds[((i + 1) & 1) * 6144];
      gload16(Ag + k0, base + sA);
      gload16(Bg + k0, base + sB);
      gload16(Bg + k0 + (size_t)64 * K, base + sB + 512);
    }
    const short* cur = &lds[(i & 1) * 6144];
    short8 af[2], bfr[4];
#pragma unroll
    for (int mt = 0; mt < 2; ++mt)
      af[mt] = *(const short8*)&cur[(quad * 64 + wm * 32 + mt * 16 + l16) * 8];
#pragma unroll
    for (int nt = 0; nt < 4; ++nt)
      bfr[nt] = *(const short8*)&cur[2048 + (quad * 128 + wn * 64 + nt * 16 + l16) * 8];
#pragma unroll
    for (int mt = 0; mt < 2; ++mt)
#pragma unroll
      for (int nt = 0; nt < 4; ++nt)
        acc[mt][nt] = __builtin_amdgcn_mfma_f32_16x16x32_bf16(af[mt], bfr[nt], acc[mt][nt], 0, 0, 0);
  }
  const int mb = row0 + wm * 32 + quad * 4;
  const int nb = col0 + wn * 64 + l16;
#pragma unroll
  for (int mt = 0; mt < 2; ++mt) {
#pragma unroll
    for (int nt = 0; nt < 4; ++nt) {
      floatx4 a4 = acc[mt][nt];
#pragma unroll
      for (int r = 0; r < 4; ++r) {
        int row = mb + mt * 16 + r;
        int col = nb + nt * 16;
        float val = a4[r];
        if (bias) val += bias[col];
        if (dogelu) val = 0.5f * val * (1.f + erff(val * 0.7071067811865475f));
        size_t idx = (size_t)row * N + col;
        if (resid) val += resid[idx];
        if (outF) outF[idx] = val;
        else outB[idx] = f2bf(val);
      }
    }
  }
}

// ---------------- bf16 MFMA GEMM, 64x64 tile, BK=32, dbuf (4 blocks/CU for N=512) ----------------
// Buffer (4096 shorts): A slot(kc,m)=(kc*64+m)*8; B at +2048, slot(kc,n)=(kc*64+n)*8.
// Waves 2x2 of 32x32; 4 MFMA/wave/iter.
__global__ __launch_bounds__(256, 4) void k_gemm64(const ushort_t* __restrict__ A,
                                                   const ushort_t* __restrict__ Bt,
                                                   const float* __restrict__ resid,
                                                   const float* __restrict__ bias,
                                                   float* __restrict__ outF,
                                                   ushort_t* __restrict__ outB,
                                                   int M, int N, int K, int dogelu) {
  __shared__ short lds[8192];
  const int tid = threadIdx.x;
  const int w = tid >> 6, lane = tid & 63;
  const int quad = lane >> 4, l16 = lane & 15;
  const int wm = w >> 1, wn = w & 1;
  int bx, by;
  xcd_swz(gridDim.x, bx, by);
  const int row0 = by * 64, col0 = bx * 64;
  const short* Ag = (const short*)A + (size_t)(row0 + lane) * K + w * 8;
  const short* Bg = (const short*)Bt + (size_t)(col0 + lane) * K + w * 8;
  floatx4 acc[2][2] = {};
  const int sA = w * 512;
  const int sB = 2048 + w * 512;
  {
    short* base = &lds[0];
    gload16(Ag, base + sA);
    gload16(Bg, base + sB);
  }
  const int nk = K >> 5;
  for (int i = 0; i < nk; ++i) {
    __syncthreads();
    if (i + 1 < nk) {
      const int k0 = (i + 1) << 5;
      short* base = &lds[((i + 1) & 1) * 4096];
      gload16(Ag + k0, base + sA);
      gload16(Bg + k0, base + sB);
    }
    const short* cur = &lds[(i & 1) * 4096];
    short8 af[2], bfr[2];
#pragma unroll
    for (int mt = 0; mt < 2; ++mt)
      af[mt] = *(const short8*)&cur[(quad * 64 + wm * 32 + mt * 16 + l16) * 8];
#pragma unroll
    for (int nt = 0; nt < 2; ++nt)
      bfr[nt] = *(const short8*)&cur[2048 + (quad * 64 + wn * 32 + nt * 16 + l16) * 8];
#pragma unroll
    for (int mt = 0; mt < 2; ++mt)
#pragma unroll
      for (int nt = 0; nt < 2; ++nt)
        acc[mt][nt] = __builtin_amdgcn_mfma_f32_16x16x32_bf16(af[mt], bfr[nt], acc[mt][nt], 0, 0, 0);
  }
  const int mb = row0 + wm * 32 + quad * 4;
  const int nb = col0 + wn * 32 + l16;
#pragma unroll
  for (int mt = 0; mt < 2; ++mt) {
#pragma unroll
    for (int nt = 0; nt < 2; ++nt) {
      floatx4 a4 = acc[mt][nt];
#pragma unroll
      for (int r = 0; r < 4; ++r) {
        int row = mb + mt * 16 + r;
        int col = nb + nt * 16;
        float val = a4[r];
        if (bias) val += bias[col];
        if (dogelu) val = 0.5f * val * (1.f + erff(val * 0.7071067811865475f));
        size_t idx = (size_t)row * N + col;
        if (resid) val += resid[idx];
        if (outF) outF[idx] = val;
        else outB[idx] = f2bf(val);
      }
    }
  }
}

// ---------------- MFMA flash attention ----------------
__global__ __launch_bounds__(256) void k_attn(const ushort_t* __restrict__ qkv,
                                              const int* __restrict__ lengths,
                                              ushort_t* __restrict__ o) {
  __shared__ ushort_t Ks[64 * 72];
  __shared__ ushort_t Vt[64 * 72];
  __shared__ ushort_t Ps[4][16 * 72];
  const int tid = threadIdx.x;
  const int w = tid >> 6, lane = tid & 63;
  const int quad = lane >> 4, l16 = lane & 15;
  const int tile = blockIdx.x & 15;
  const int bh = blockIdx.x >> 4;
  const int b = bh >> 3, h = bh & 7;
  const int len = lengths[b];
  const int tqa = tile * 64 + w * 16 + l16;
  const ushort_t* qp = qkv + ((size_t)(b * TT + tqa)) * 1536 + h * HSZ + quad * 8;
  short8 qf0 = *(const short8*)qp;
  short8 qf1 = *(const short8*)(qp + 32);
  floatx4 oacc[4] = {};
  float mrun[4], lrun[4];
#pragma unroll
  for (int r = 0; r < 4; ++r) { mrun[r] = -1e30f; lrun[r] = 0.f; }
  const int skey = tid >> 2, sseg = (tid & 3) << 4;
  const int vkp = (tid & 31) << 1, vds = (tid >> 5) << 3;
  const int nkt = (len + 63) >> 6;
  for (int kt = 0; kt < nkt; ++kt) {
    const int s0 = kt * 64;
    __syncthreads();
    {
      const ushort_t* kp = qkv + ((size_t)(b * TT + s0 + skey)) * 1536 + 512 + h * HSZ + sseg;
      short8 k0 = *(const short8*)kp;
      short8 k1 = *(const short8*)(kp + 8);
      *(short8*)&Ks[skey * 72 + sseg] = k0;
      *(short8*)&Ks[skey * 72 + sseg + 8] = k1;
      const ushort_t* vp0 = qkv + ((size_t)(b * TT + s0 + vkp)) * 1536 + 1024 + h * HSZ + vds;
      short8 v0 = *(const short8*)vp0;
      short8 v1 = *(const short8*)(vp0 + 1536);
#pragma unroll
      for (int i = 0; i < 8; ++i) {
        ushort2 pr;
        pr.x = (ushort_t)v0[i];
        pr.y = (ushort_t)v1[i];
        *(ushort2*)&Vt[(vds + i) * 72 + vkp] = pr;
      }
    }
    __syncthreads();
    floatx4 sacc[4] = {};
#pragma unroll
    for (int nt = 0; nt < 4; ++nt) {
      short8 kf0 = *(const short8*)&Ks[(nt * 16 + l16) * 72 + quad * 8];
      short8 kf1 = *(const short8*)&Ks[(nt * 16 + l16) * 72 + 32 + quad * 8];
      sacc[nt] = __builtin_amdgcn_mfma_f32_16x16x32_bf16(qf0, kf0, sacc[nt], 0, 0, 0);
      sacc[nt] = __builtin_amdgcn_mfma_f32_16x16x32_bf16(qf1, kf1, sacc[nt], 0, 0, 0);
    }
    float p[4][4], mx[4];
#pragma unroll
    for (int r = 0; r < 4; ++r) {
      float m = -1e30f;
#pragma unroll
      for (int nt = 0; nt < 4; ++nt) {
        float s = (s0 + nt * 16 + l16 < len) ? sacc[nt][r] * 0.125f : -1e30f;
        p[nt][r] = s;
        m = fmaxf(m, s);
      }
      mx[r] = m;
    }
#pragma unroll
    for (int off = 1; off < 16; off <<= 1) {
#pragma unroll
      for (int r = 0; r < 4; ++r) mx[r] = fmaxf(mx[r], __shfl_xor(mx[r], off, 64));
    }
    float corr[4], rs[4];
#pragma unroll
    for (int r = 0; r < 4; ++r) {
      float mnew = fmaxf(mrun[r], mx[r]);
      corr[r] = __expf(mrun[r] - mnew);
      mrun[r] = mnew;
      float s = 0.f;
#pragma unroll
      for (int nt = 0; nt < 4; ++nt) {
        float e = __expf(p[nt][r] - mnew);
        p[nt][r] = e;
        s += e;
      }
      rs[r] = s;
    }
#pragma unroll
    for (int off = 1; off < 16; off <<= 1) {
#pragma unroll
      for (int r = 0; r < 4; ++r) rs[r] += __shfl_xor(rs[r], off, 64);
    }
#pragma unroll
    for (int r = 0; r < 4; ++r) {
      lrun[r] = lrun[r] * corr[r] + rs[r];
#pragma unroll
      for (int nt = 0; nt < 4; ++nt) {
        oacc[nt][r] *= corr[r];
        Ps[w][(quad * 4 + r) * 72 + nt * 16 + l16] = f2bf(p[nt][r]);
      }
    }
    short8 pf0 = *(const short8*)&Ps[w][l16 * 72 + quad * 8];
    short8 pf1 = *(const short8*)&Ps[w][l16 * 72 + 32 + quad * 8];
#pragma unroll
    for (int nt = 0; nt < 4; ++nt) {
      short8 vf0 = *(const short8*)&Vt[(nt * 16 + l16) * 72 + quad * 8];
      short8 vf1 = *(const short8*)&Vt[(nt * 16 + l16) * 72 + 32 + quad * 8];
      oacc[nt] = __builtin_amdgcn_mfma_f32_16x16x32_bf16(pf0, vf0, oacc[nt], 0, 0, 0);
      oacc[nt] = __builtin_amdgcn_mfma_f32_16x16x32_bf16(pf1, vf1, oacc[nt], 0, 0, 0);
    }
  }
#pragma unroll
  for (int r = 0; r < 4; ++r) {
    int t = tile * 64 + w * 16 + quad * 4 + r;
    float inv = (t < len) ? 1.f / lrun[r] : 0.f;
    ushort_t* op = o + ((size_t)(b * TT + t)) * DD + h * HSZ + l16;
#pragma unroll
    for (int nt = 0; nt < 4; ++nt) op[nt * 16] = f2bf(oacc[nt][r] * inv);
  }
}

// ---------------- pool softmax: scores -> weights (per batch) ----------------
__global__ __launch_bounds__(256) void k_softw(const float* __restrict__ scores,
                                               const int* __restrict__ lengths,
                                               float* __restrict__ wts) {
  __shared__ float red[8];
  int tid = threadIdx.x, b = blockIdx.x;
  int len = lengths[b];
  const float* sb = scores + b * TT;
  float m = -1e30f;
  for (int t = tid; t < len; t += 256) m = fmaxf(m, sb[t]);
#pragma unroll
  for (int off = 32; off; off >>= 1) m = fmaxf(m, __shfl_down(m, off, 64));
  if ((tid & 63) == 0) red[tid >> 6] = m;
  __syncthreads();
  m = fmaxf(fmaxf(red[0], red[1]), fmaxf(red[2], red[3]));
  float ssum = 0.f;
  for (int t = tid; t < len; t += 256) ssum += __expf(sb[t] - m);
#pragma unroll
  for (int off = 32; off; off >>= 1) ssum += __shfl_down(ssum, off, 64);
  if ((tid & 63) == 0) red[4 + (tid >> 6)] = ssum;
  __syncthreads();
  float inv = 1.f / (red[4] + red[5] + red[6] + red[7]);
  for (int t = tid; t < TT; t += 256)
    wts[b * TT + t] = (t < len) ? __expf(sb[t] - m) * inv : 0.f;
}

// ---------------- weighted sum partials: grid (B, 16), 64 rows each ----------------
__global__ __launch_bounds__(256) void k_wsum(const float* __restrict__ xf,
                                              const float* __restrict__ wts,
                                              float* __restrict__ partial) {
  int b = blockIdx.x, c = blockIdx.y, tid = threadIdx.x;
  const float* xb = xf + ((size_t)b * TT + c * 64) * DD;
  const float* wb = wts + b * TT + c * 64;
  float a0 = 0.f, a1 = 0.f;
  for (int t = 0; t < 64; ++t) {
    float wv = wb[t];
    a0 += wv * xb[(size_t)t * DD + tid];
    a1 += wv * xb[(size_t)t * DD + tid + 256];
  }
  float* pp = partial + ((size_t)b * 16 + c) * DD;
  pp[tid] = a0;
  pp[tid + 256] = a1;
}

// ---------------- classification head (reduces the 16 partials) ----------------
__global__ __launch_bounds__(64) void k_head(const float* __restrict__ partial,
                                             const float* __restrict__ head_w,
                                             const float* __restrict__ head_b,
                                             float* __restrict__ out) {
  __shared__ float ssum[DD];
  int b = blockIdx.x, tid = threadIdx.x;
  for (int d = tid; d < DD; d += 64) {
    float s = 0.f;
#pragma unroll
    for (int c = 0; c < 16; ++c) s += partial[((size_t)b * 16 + c) * DD + d];
    ssum[d] = s;
  }
  __syncthreads();
  if (tid < 49) {
    float s = head_b[tid];
    for (int d = 0; d < DD; ++d) s += ssum[d] * head_w[d * 49 + tid];
    out[b * 49 + tid] = s;
  }
}

extern "C" void kernel_launch(void* const* d_in, const int* in_sizes, int n_in,
                              void* d_out, int out_size, void* d_ws, size_t ws_size,
                              hipStream_t stream) {
  const int* code = (const int*)d_in[0];
  const int* lengths = (const int*)d_in[1];
  const float* emb = (const float*)d_in[2];
  const float* Wq = (const float*)d_in[3];
  const float* Wk = (const float*)d_in[4];
  const float* Wv = (const float*)d_in[5];
  const float* Wo = (const float*)d_in[6];
  const float* bo = (const float*)d_in[7];
  const float* W1 = (const float*)d_in[8];
  const float* b1 = (const float*)d_in[9];
  const float* W2 = (const float*)d_in[10];
  const float* b2 = (const float*)d_in[11];
  const float* ln1_g = (const float*)d_in[12];
  const float* ln1_b = (const float*)d_in[13];
  const float* ln2_g = (const float*)d_in[14];
  const float* ln2_b = (const float*)d_in[15];
  const float* lnf_g = (const float*)d_in[16];
  const float* lnf_b = (const float*)d_in[17];
  const float* attn_w = (const float*)d_in[18];
  const float* attn_b = (const float*)d_in[19];
  const float* head_w = (const float*)d_in[20];
  const float* head_b = (const float*)d_in[21];
  float* out = (float*)d_out;

  const size_t NTOK = (size_t)BB * TT;  // 8192
  float* x = (float*)d_ws;                       // 8192*512 fp32
  ushort_t* xn = (ushort_t*)(x + NTOK * DD);     // 8192*512 bf16
  ushort_t* un = xn + NTOK * DD;                 // union: qkv | h1 | xf
  ushort_t* qkv = un;
  ushort_t* h1 = un;
  float* xf = (float*)un;
  ushort_t* wqt = un + (size_t)NTOK * FF4;
  ushort_t* wot = wqt + (size_t)LL * 1536 * 512;
  ushort_t* w1t = wot + (size_t)LL * 512 * 512;
  ushort_t* w2t = w1t + (size_t)LL * 512 * FF4;
  float* scores = (float*)(w2t + (size_t)LL * FF4 * 512);  // 8192
  float* wts = scores + NTOK;                              // 8192
  float* partial = wts + NTOK;                             // 8*16*512

  k_transpose<<<dim3(8, 1, 48), 256, 0, stream>>>(Wq, wqt,             64, (long)512 * 64, 8, (long)1536 * 512, (long)64 * 512, 512);
  k_transpose<<<dim3(8, 1, 48), 256, 0, stream>>>(Wk, wqt + 512 * 512,  64, (long)512 * 64, 8, (long)1536 * 512, (long)64 * 512, 512);
  k_transpose<<<dim3(8, 1, 48), 256, 0, stream>>>(Wv, wqt + 1024 * 512, 64, (long)512 * 64, 8, (long)1536 * 512, (long)64 * 512, 512);
  k_transpose<<<dim3(8, 8, 6), 256, 0, stream>>>(Wo, wot, 512, (long)512 * 512, 1, (long)512 * 512, 0, 512);
  k_transpose<<<dim3(8, 32, 6), 256, 0, stream>>>(W1, w1t, 2048, (long)512 * 2048, 1, (long)2048 * 512, 0, 512);
  k_transpose<<<dim3(32, 8, 6), 256, 0, stream>>>(W2, w2t, 512, (long)2048 * 512, 1, (long)512 * 2048, 0, 2048);

  k_embed<<<dim3((unsigned)((NTOK * DD) / 256)), dim3(256), 0, stream>>>(code, emb, x);

  for (int l = 0; l < LL; ++l) {
    k_ln<<<dim3(NTOK / 4), 256, 0, stream>>>(x, xn, nullptr, ln1_g + l * DD, ln1_b + l * DD,
                                             nullptr, nullptr, nullptr);
    // QKV: 64x128 tiles -> 1536 blocks (6/CU)
    k_gemm<<<dim3(12, 128), 256, 0, stream>>>(xn, wqt + (size_t)l * 1536 * 512, nullptr, nullptr,
                                              nullptr, qkv, (int)NTOK, 1536, 512, 0);
    k_attn<<<dim3(BB * HH * (TT / 64)), 256, 0, stream>>>(qkv, lengths, xn);
    // Wo + residual: 64x64 tiles -> 1024 blocks (4/CU)
    k_gemm64<<<dim3(8, 128), 256, 0, stream>>>(xn, wot + (size_t)l * 512 * 512, x, bo + l * DD,
                                               x, nullptr, (int)NTOK, 512, 512, 0);
    k_ln<<<dim3(NTOK / 4), 256, 0, stream>>>(x, xn, nullptr, ln2_g + l * DD, ln2_b + l * DD,
                                             nullptr, nullptr, nullptr);
    // W1 + bias + GELU: 64x128 tiles -> 2048 blocks (6/CU, LDS-limited)
    k_gemm<<<dim3(16, 128), 256, 0, stream>>>(xn, w1t + (size_t)l * 512 * FF4, nullptr, b1 + l * FF4,
                                              nullptr, h1, (int)NTOK, FF4, 512, 1);
    // W2 + residual: 64x64 tiles -> 1024 blocks (4/CU)
    k_gemm64<<<dim3(8, 128), 256, 0, stream>>>(h1, w2t + (size_t)l * FF4 * 512, x, b2 + l * DD,
                                               x, nullptr, (int)NTOK, 512, FF4, 0);
  }
  k_ln<<<dim3(NTOK / 4), 256, 0, stream>>>(x, nullptr, xf, lnf_g, lnf_b,
                                           attn_w, attn_b, scores);
  k_softw<<<dim3(BB), 256, 0, stream>>>(scores, lengths, wts);
  k_wsum<<<dim3(BB, 16), 256, 0, stream>>>(xf, wts, partial);
  k_head<<<dim3(BB), 64, 0, stream>>>(partial, head_w, head_b, out);
}

// Round 8
// 1769.323 us; speedup vs baseline: 1.0441x; 1.0441x over previous
//
#include <hip/hip_runtime.h>
#include <math.h>

#define TT 1024
#define BB 8
#define DD 512
#define HH 8
#define HSZ 64
#define LL 6
#define FF4 2048

typedef __attribute__((ext_vector_type(8))) short short8;
typedef __attribute__((ext_vector_type(4))) float floatx4;
typedef unsigned short ushort_t;
typedef unsigned int uint_t;

__device__ __forceinline__ ushort_t f2bf(float f) {
  uint_t u = __float_as_uint(f);
  u += 0x7fff + ((u >> 16) & 1);  // RNE
  return (ushort_t)(u >> 16);
}
__device__ __forceinline__ float bf2f(ushort_t h) {
  return __uint_as_float(((uint_t)h) << 16);
}

// Packed MFMA-fragment layout for a [rows x Kd] bf16 matrix:
// tile (r16=row>>4, c32=col>>5); element index =
//   ((r16*(Kd>>5)+c32)<<9) + (((col>>3)&3)*16 + (row&15))*8 + (col&7)
// A wave's fragment (16 rows x 32 cols) is one contiguous 1KB chunk,
// lane i holding bytes [i*16, i*16+16) -> one coalesced global_load_dwordx4.

// ---------------- embed + positional encoding ----------------
__global__ __launch_bounds__(256) void k_embed(const int* __restrict__ code,
                                               const float* __restrict__ emb,
                                               float* __restrict__ x) {
  int idx = blockIdx.x * 256 + threadIdx.x;  // over B*T*D
  int c = idx & (DD - 1);
  int bt = idx >> 9;
  int t = bt & (TT - 1);
  int f = c >> 4, e = c & 15;
  int vv = code[bt * 32 + f];
  int i = c >> 1;
  float freq = expf((float)(2 * i) * (-9.210340371976184f / 512.f));
  float ang = (float)t * freq;
  float pe = (c & 1) ? cosf(ang) : sinf(ang);
  x[idx] = emb[vv * 16 + e] + pe;
}

// ---------------- layernorm: fp32 in -> packed bf16 (or linear fp32 + scores) ----------------
__global__ __launch_bounds__(256) void k_ln(const float* __restrict__ x,
                                            ushort_t* __restrict__ yB,
                                            float* __restrict__ yF,
                                            const float* __restrict__ g,
                                            const float* __restrict__ b,
                                            const float* __restrict__ aw,
                                            const float* __restrict__ ab,
                                            float* __restrict__ scores) {
  int wave = threadIdx.x >> 6, lane = threadIdx.x & 63;
  int row = blockIdx.x * 4 + wave;
  const float* xr = x + (size_t)row * DD;
  float v[8];
  *(float4*)&v[0] = *(const float4*)(xr + lane * 8);
  *(float4*)&v[4] = *(const float4*)(xr + lane * 8 + 4);
  float s = 0.f;
#pragma unroll
  for (int j = 0; j < 8; ++j) s += v[j];
#pragma unroll
  for (int off = 32; off; off >>= 1) s += __shfl_down(s, off, 64);
  float mean = __shfl(s, 0, 64) * (1.f / DD);
  float qv = 0.f;
#pragma unroll
  for (int j = 0; j < 8; ++j) { float d = v[j] - mean; qv += d * d; }
#pragma unroll
  for (int off = 32; off; off >>= 1) qv += __shfl_down(qv, off, 64);
  float rs = rsqrtf(__shfl(qv, 0, 64) * (1.f / DD) + 1e-5f);
  float ov[8];
  float sdot = 0.f;
#pragma unroll
  for (int e = 0; e < 8; ++e) {
    int c = lane * 8 + e;
    ov[e] = (v[e] - mean) * rs * g[c] + b[c];
    if (scores) sdot += ov[e] * aw[c];
  }
  if (yB) {
    short8 o8;
#pragma unroll
    for (int e = 0; e < 8; ++e) o8[e] = (short)f2bf(ov[e]);
    // packed addr: Kd=512, tile=(row>>4, lane>>2), inner=(lane&3)*16+(row&15)
    size_t ad = (((size_t)(row >> 4) * 16 + (lane >> 2)) << 9) + ((lane & 3) * 16 + (row & 15)) * 8;
    *(short8*)(yB + ad) = o8;
  } else {
    float* yr = yF + (size_t)row * DD + lane * 8;
    *(float4*)yr = *(float4*)&ov[0];
    *(float4*)(yr + 4) = *(float4*)&ov[4];
  }
  if (scores) {
#pragma unroll
    for (int off = 32; off; off >>= 1) sdot += __shfl_down(sdot, off, 64);
    if (lane == 0) scores[row] = sdot + ab[0];
  }
}

// ---------------- fp32 weights -> packed bf16 B-operand ----------------
// in: mz-th source matrix at in + mz*in_ms, layout [k][n], row stride Nin.
// out: packed matrix (out + (mz/nh)*os_l), n-offset (mz%nh)*nblk + blockIdx.y*64.
__global__ __launch_bounds__(256) void k_packw(const float* __restrict__ in,
                                               ushort_t* __restrict__ out,
                                               int Nin, long in_ms, int nh,
                                               long os_l, int nblk, int Kout) {
  __shared__ float t4[64][65];
  int mz = blockIdx.z;
  const float* ip = in + (size_t)mz * in_ms;
  ushort_t* op = out + (size_t)(mz / nh) * os_l;
  int nbase = (mz % nh) * nblk + blockIdx.y * 64;
  int k0 = blockIdx.x * 64;
  int cc = threadIdx.x & 63, r0 = threadIdx.x >> 6;
#pragma unroll
  for (int i = 0; i < 16; ++i) {
    int r = r0 * 16 + i;
    t4[r][cc] = ip[(size_t)(k0 + r) * Nin + (nbase - (mz % nh) * nblk) + cc];
  }
  __syncthreads();
#pragma unroll
  for (int half = 0; half < 2; ++half) {
    int c = threadIdx.x + half * 256;  // 0..511: joct=c>>6, n_local=c&63
    int joct = c >> 6, nl = c & 63;
    int n = nbase + nl, k = k0 + joct * 8;
    short8 v8;
#pragma unroll
    for (int e = 0; e < 8; ++e) v8[e] = (short)f2bf(t4[joct * 8 + e][nl]);
    size_t ad = (((size_t)(n >> 4) * (Kout >> 5) + (k >> 5)) << 9) + (((k >> 3) & 3) * 16 + (n & 15)) * 8;
    *(short8*)(op + ad) = v8;
  }
}

// ---------------- packed-fragment MFMA GEMM: no LDS staging, no barriers ----------------
// One wave per block, 64x64 wave tile, register-double-buffered K-loop.
// mode 0: outB linear bf16; mode 1: outF = acc + bias + resid (fp32 linear);
// mode 2: outB packed bf16 of gelu(acc+bias)  (h1 for the next GEMM).
__global__ __launch_bounds__(64) void k_pgemm(const ushort_t* __restrict__ Apk,
                                              const ushort_t* __restrict__ Bpk,
                                              const float* __restrict__ resid,
                                              const float* __restrict__ bias,
                                              float* __restrict__ outF,
                                              ushort_t* __restrict__ outB,
                                              int M, int N, int K, int mode) {
  __shared__ ushort_t Cb[64 * 80];
  const int lane = threadIdx.x;
  const int quad = lane >> 4, l16 = lane & 15;
  const int gx = N >> 6;
  int id = blockIdx.x;
  int bx = (id >> 3) % gx;
  int by = (id / (8 * gx)) * 8 + (id & 7);  // same-row tiles share an XCD
  const int row0 = by * 64, col0 = bx * 64;
  const int nk = K >> 5;
  const ushort_t* Ab = Apk + (((size_t)(row0 >> 4) * nk) << 9) + lane * 8;
  const ushort_t* Bb = Bpk + (((size_t)(col0 >> 4) * nk) << 9) + lane * 8;
  floatx4 acc[4][4] = {};
  short8 aA[4], bA[4], aB[4], bB[4];
#pragma unroll
  for (int mt = 0; mt < 4; ++mt) aA[mt] = *(const short8*)(Ab + (((size_t)mt * nk) << 9));
#pragma unroll
  for (int nt = 0; nt < 4; ++nt) bA[nt] = *(const short8*)(Bb + (((size_t)nt * nk) << 9));
  int kc = 0;
  for (; kc + 2 < nk; kc += 2) {
#pragma unroll
    for (int mt = 0; mt < 4; ++mt) aB[mt] = *(const short8*)(Ab + (((size_t)(mt * nk + kc + 1)) << 9));
#pragma unroll
    for (int nt = 0; nt < 4; ++nt) bB[nt] = *(const short8*)(Bb + (((size_t)(nt * nk + kc + 1)) << 9));
#pragma unroll
    for (int mt = 0; mt < 4; ++mt)
#pragma unroll
      for (int nt = 0; nt < 4; ++nt)
        acc[mt][nt] = __builtin_amdgcn_mfma_f32_16x16x32_bf16(aA[mt], bA[nt], acc[mt][nt], 0, 0, 0);
#pragma unroll
    for (int mt = 0; mt < 4; ++mt) aA[mt] = *(const short8*)(Ab + (((size_t)(mt * nk + kc + 2)) << 9));
#pragma unroll
    for (int nt = 0; nt < 4; ++nt) bA[nt] = *(const short8*)(Bb + (((size_t)(nt * nk + kc + 2)) << 9));
#pragma unroll
    for (int mt = 0; mt < 4; ++mt)
#pragma unroll
      for (int nt = 0; nt < 4; ++nt)
        acc[mt][nt] = __builtin_amdgcn_mfma_f32_16x16x32_bf16(aB[mt], bB[nt], acc[mt][nt], 0, 0, 0);
  }
  // kc == nk-2 (nk always even): last pair
#pragma unroll
  for (int mt = 0; mt < 4; ++mt) aB[mt] = *(const short8*)(Ab + (((size_t)(mt * nk + kc + 1)) << 9));
#pragma unroll
  for (int nt = 0; nt < 4; ++nt) bB[nt] = *(const short8*)(Bb + (((size_t)(nt * nk + kc + 1)) << 9));
#pragma unroll
  for (int mt = 0; mt < 4; ++mt)
#pragma unroll
    for (int nt = 0; nt < 4; ++nt)
      acc[mt][nt] = __builtin_amdgcn_mfma_f32_16x16x32_bf16(aA[mt], bA[nt], acc[mt][nt], 0, 0, 0);
#pragma unroll
  for (int mt = 0; mt < 4; ++mt)
#pragma unroll
    for (int nt = 0; nt < 4; ++nt)
      acc[mt][nt] = __builtin_amdgcn_mfma_f32_16x16x32_bf16(aB[mt], bB[nt], acc[mt][nt], 0, 0, 0);

  if (mode == 2) {
    // gelu(acc+bias) -> per-wave LDS -> packed bf16 (Kd = N of this GEMM)
#pragma unroll
    for (int mt = 0; mt < 4; ++mt)
#pragma unroll
      for (int nt = 0; nt < 4; ++nt) {
        floatx4 a4 = acc[mt][nt];
#pragma unroll
        for (int r = 0; r < 4; ++r) {
          float val = a4[r] + bias[col0 + nt * 16 + l16];
          val = 0.5f * val * (1.f + erff(val * 0.7071067811865475f));
          Cb[(mt * 16 + quad * 4 + r) * 80 + nt * 16 + l16] = f2bf(val);
        }
      }
#pragma unroll
    for (int mt2 = 0; mt2 < 4; ++mt2)
#pragma unroll
      for (int kt2 = 0; kt2 < 2; ++kt2) {
        short8 v8 = *(const short8*)&Cb[(mt2 * 16 + l16) * 80 + kt2 * 32 + quad * 8];
        size_t ad = ((((size_t)(row0 >> 4) + mt2) * (N >> 5) + (col0 >> 5) + kt2) << 9) + lane * 8;
        *(short8*)(outB + ad) = v8;
      }
  } else {
#pragma unroll
    for (int mt = 0; mt < 4; ++mt)
#pragma unroll
      for (int nt = 0; nt < 4; ++nt) {
        floatx4 a4 = acc[mt][nt];
#pragma unroll
        for (int r = 0; r < 4; ++r) {
          int row = row0 + mt * 16 + quad * 4 + r;
          int col = col0 + nt * 16 + l16;
          float val = a4[r];
          if (bias) val += bias[col];
          size_t idx = (size_t)row * N + col;
          if (mode == 1) outF[idx] = val + resid[idx];
          else outB[idx] = f2bf(val);
        }
      }
  }
}

// ---------------- MFMA flash attention (qkv linear bf16 in, packed bf16 out) ----------------
__global__ __launch_bounds__(256) void k_attn(const ushort_t* __restrict__ qkv,
                                              const int* __restrict__ lengths,
                                              ushort_t* __restrict__ o) {
  __shared__ ushort_t Ks[64 * 72];
  __shared__ ushort_t Vt[64 * 72];
  __shared__ ushort_t Ps[4][16 * 80];
  const int tid = threadIdx.x;
  const int w = tid >> 6, lane = tid & 63;
  const int quad = lane >> 4, l16 = lane & 15;
  const int tile = blockIdx.x & 15;
  const int bh = blockIdx.x >> 4;
  const int b = bh >> 3, h = bh & 7;
  const int len = lengths[b];
  const int tqa = tile * 64 + w * 16 + l16;
  const ushort_t* qp = qkv + ((size_t)(b * TT + tqa)) * 1536 + h * HSZ + quad * 8;
  short8 qf0 = *(const short8*)qp;
  short8 qf1 = *(const short8*)(qp + 32);
  floatx4 oacc[4] = {};
  float mrun[4], lrun[4];
#pragma unroll
  for (int r = 0; r < 4; ++r) { mrun[r] = -1e30f; lrun[r] = 0.f; }
  const int skey = tid >> 2, sseg = (tid & 3) << 4;
  const int vkp = (tid & 31) << 1, vds = (tid >> 5) << 3;
  const int nkt = (len + 63) >> 6;
  for (int kt = 0; kt < nkt; ++kt) {
    const int s0 = kt * 64;
    __syncthreads();
    {
      const ushort_t* kp = qkv + ((size_t)(b * TT + s0 + skey)) * 1536 + 512 + h * HSZ + sseg;
      short8 k0 = *(const short8*)kp;
      short8 k1 = *(const short8*)(kp + 8);
      *(short8*)&Ks[skey * 72 + sseg] = k0;
      *(short8*)&Ks[skey * 72 + sseg + 8] = k1;
      const ushort_t* vp0 = qkv + ((size_t)(b * TT + s0 + vkp)) * 1536 + 1024 + h * HSZ + vds;
      short8 v0 = *(const short8*)vp0;
      short8 v1 = *(const short8*)(vp0 + 1536);
#pragma unroll
      for (int i = 0; i < 8; ++i) {
        ushort2 pr;
        pr.x = (ushort_t)v0[i];
        pr.y = (ushort_t)v1[i];
        *(ushort2*)&Vt[(vds + i) * 72 + vkp] = pr;
      }
    }
    __syncthreads();
    floatx4 sacc[4] = {};
#pragma unroll
    for (int nt = 0; nt < 4; ++nt) {
      short8 kf0 = *(const short8*)&Ks[(nt * 16 + l16) * 72 + quad * 8];
      short8 kf1 = *(const short8*)&Ks[(nt * 16 + l16) * 72 + 32 + quad * 8];
      sacc[nt] = __builtin_amdgcn_mfma_f32_16x16x32_bf16(qf0, kf0, sacc[nt], 0, 0, 0);
      sacc[nt] = __builtin_amdgcn_mfma_f32_16x16x32_bf16(qf1, kf1, sacc[nt], 0, 0, 0);
    }
    float p[4][4], mx[4];
#pragma unroll
    for (int r = 0; r < 4; ++r) {
      float m = -1e30f;
#pragma unroll
      for (int nt = 0; nt < 4; ++nt) {
        float s = (s0 + nt * 16 + l16 < len) ? sacc[nt][r] * 0.125f : -1e30f;
        p[nt][r] = s;
        m = fmaxf(m, s);
      }
      mx[r] = m;
    }
#pragma unroll
    for (int off = 1; off < 16; off <<= 1) {
#pragma unroll
      for (int r = 0; r < 4; ++r) mx[r] = fmaxf(mx[r], __shfl_xor(mx[r], off, 64));
    }
    float corr[4], rs[4];
#pragma unroll
    for (int r = 0; r < 4; ++r) {
      float mnew = fmaxf(mrun[r], mx[r]);
      corr[r] = __expf(mrun[r] - mnew);
      mrun[r] = mnew;
      float s = 0.f;
#pragma unroll
      for (int nt = 0; nt < 4; ++nt) {
        float e = __expf(p[nt][r] - mnew);
        p[nt][r] = e;
        s += e;
      }
      rs[r] = s;
    }
#pragma unroll
    for (int off = 1; off < 16; off <<= 1) {
#pragma unroll
      for (int r = 0; r < 4; ++r) rs[r] += __shfl_xor(rs[r], off, 64);
    }
#pragma unroll
    for (int r = 0; r < 4; ++r) {
      lrun[r] = lrun[r] * corr[r] + rs[r];
#pragma unroll
      for (int nt = 0; nt < 4; ++nt) {
        oacc[nt][r] *= corr[r];
        Ps[w][(quad * 4 + r) * 80 + nt * 16 + l16] = f2bf(p[nt][r]);
      }
    }
    short8 pf0 = *(const short8*)&Ps[w][l16 * 80 + quad * 8];
    short8 pf1 = *(const short8*)&Ps[w][l16 * 80 + 32 + quad * 8];
#pragma unroll
    for (int nt = 0; nt < 4; ++nt) {
      short8 vf0 = *(const short8*)&Vt[(nt * 16 + l16) * 72 + quad * 8];
      short8 vf1 = *(const short8*)&Vt[(nt * 16 + l16) * 72 + 32 + quad * 8];
      oacc[nt] = __builtin_amdgcn_mfma_f32_16x16x32_bf16(pf0, vf0, oacc[nt], 0, 0, 0);
      oacc[nt] = __builtin_amdgcn_mfma_f32_16x16x32_bf16(pf1, vf1, oacc[nt], 0, 0, 0);
    }
  }
  // epilogue: per-wave LDS shuffle into packed-A layout (Kd=512)
#pragma unroll
  for (int r = 0; r < 4; ++r) {
    int t = tile * 64 + w * 16 + quad * 4 + r;
    float inv = (t < len) ? 1.f / lrun[r] : 0.f;  // row mask
#pragma unroll
    for (int nt = 0; nt < 4; ++nt)
      Ps[w][(quad * 4 + r) * 80 + nt * 16 + l16] = f2bf(oacc[nt][r] * inv);
  }
  const int mtile = b * 64 + tile * 4 + w;  // (b*TT + tile*64 + w*16) >> 4
#pragma unroll
  for (int kt2 = 0; kt2 < 2; ++kt2) {
    short8 v8 = *(const short8*)&Ps[w][l16 * 80 + kt2 * 32 + quad * 8];
    size_t ad = (((size_t)mtile * 16 + h * 2 + kt2) << 9) + lane * 8;
    *(short8*)(o + ad) = v8;
  }
}

// ---------------- pool softmax: scores -> weights (per batch) ----------------
__global__ __launch_bounds__(256) void k_softw(const float* __restrict__ scores,
                                               const int* __restrict__ lengths,
                                               float* __restrict__ wts) {
  __shared__ float red[8];
  int tid = threadIdx.x, b = blockIdx.x;
  int len = lengths[b];
  const float* sb = scores + b * TT;
  float m = -1e30f;
  for (int t = tid; t < len; t += 256) m = fmaxf(m, sb[t]);
#pragma unroll
  for (int off = 32; off; off >>= 1) m = fmaxf(m, __shfl_down(m, off, 64));
  if ((tid & 63) == 0) red[tid >> 6] = m;
  __syncthreads();
  m = fmaxf(fmaxf(red[0], red[1]), fmaxf(red[2], red[3]));
  float ssum = 0.f;
  for (int t = tid; t < len; t += 256) ssum += __expf(sb[t] - m);
#pragma unroll
  for (int off = 32; off; off >>= 1) ssum += __shfl_down(ssum, off, 64);
  if ((tid & 63) == 0) red[4 + (tid >> 6)] = ssum;
  __syncthreads();
  float inv = 1.f / (red[4] + red[5] + red[6] + red[7]);
  for (int t = tid; t < TT; t += 256)
    wts[b * TT + t] = (t < len) ? __expf(sb[t] - m) * inv : 0.f;
}

// ---------------- weighted sum partials: grid (B, 16), 64 rows each ----------------
__global__ __launch_bounds__(256) void k_wsum(const float* __restrict__ xf,
                                              const float* __restrict__ wts,
                                              float* __restrict__ partial) {
  int b = blockIdx.x, c = blockIdx.y, tid = threadIdx.x;
  const float* xb = xf + ((size_t)b * TT + c * 64) * DD;
  const float* wb = wts + b * TT + c * 64;
  float a0 = 0.f, a1 = 0.f;
  for (int t = 0; t < 64; ++t) {
    float wv = wb[t];
    a0 += wv * xb[(size_t)t * DD + tid];
    a1 += wv * xb[(size_t)t * DD + tid + 256];
  }
  float* pp = partial + ((size_t)b * 16 + c) * DD;
  pp[tid] = a0;
  pp[tid + 256] = a1;
}

// ---------------- classification head (reduces the 16 partials) ----------------
__global__ __launch_bounds__(64) void k_head(const float* __restrict__ partial,
                                             const float* __restrict__ head_w,
                                             const float* __restrict__ head_b,
                                             float* __restrict__ out) {
  __shared__ float ssum[DD];
  int b = blockIdx.x, tid = threadIdx.x;
  for (int d = tid; d < DD; d += 64) {
    float s = 0.f;
#pragma unroll
    for (int c = 0; c < 16; ++c) s += partial[((size_t)b * 16 + c) * DD + d];
    ssum[d] = s;
  }
  __syncthreads();
  if (tid < 49) {
    float s = head_b[tid];
    for (int d = 0; d < DD; ++d) s += ssum[d] * head_w[d * 49 + tid];
    out[b * 49 + tid] = s;
  }
}

extern "C" void kernel_launch(void* const* d_in, const int* in_sizes, int n_in,
                              void* d_out, int out_size, void* d_ws, size_t ws_size,
                              hipStream_t stream) {
  const int* code = (const int*)d_in[0];
  const int* lengths = (const int*)d_in[1];
  const float* emb = (const float*)d_in[2];
  const float* Wq = (const float*)d_in[3];
  const float* Wk = (const float*)d_in[4];
  const float* Wv = (const float*)d_in[5];
  const float* Wo = (const float*)d_in[6];
  const float* bo = (const float*)d_in[7];
  const float* W1 = (const float*)d_in[8];
  const float* b1 = (const float*)d_in[9];
  const float* W2 = (const float*)d_in[10];
  const float* b2 = (const float*)d_in[11];
  const float* ln1_g = (const float*)d_in[12];
  const float* ln1_b = (const float*)d_in[13];
  const float* ln2_g = (const float*)d_in[14];
  const float* ln2_b = (const float*)d_in[15];
  const float* lnf_g = (const float*)d_in[16];
  const float* lnf_b = (const float*)d_in[17];
  const float* attn_w = (const float*)d_in[18];
  const float* attn_b = (const float*)d_in[19];
  const float* head_w = (const float*)d_in[20];
  const float* head_b = (const float*)d_in[21];
  float* out = (float*)d_out;

  const size_t NTOK = (size_t)BB * TT;  // 8192
  float* x = (float*)d_ws;                       // 8192*512 fp32
  ushort_t* xn = (ushort_t*)(x + NTOK * DD);     // 8192*512 bf16 (packed)
  ushort_t* un = xn + NTOK * DD;                 // union: qkv | h1 | xf
  ushort_t* qkv = un;                            // linear bf16
  ushort_t* h1 = un;                             // packed bf16
  float* xf = (float*)un;
  ushort_t* wqpk = un + (size_t)NTOK * FF4;      // packed 6x 1536x512
  ushort_t* wopk = wqpk + (size_t)LL * 1536 * 512;
  ushort_t* w1pk = wopk + (size_t)LL * 512 * 512;
  ushort_t* w2pk = w1pk + (size_t)LL * 512 * FF4;
  float* scores = (float*)(w2pk + (size_t)LL * FF4 * 512);  // 8192
  float* wts = scores + NTOK;                               // 8192
  float* partial = wts + NTOK;                              // 8*16*512

  // weight packing (fp32 [k][n] -> packed bf16 fragments)
  k_packw<<<dim3(8, 1, 48), 256, 0, stream>>>(Wq, wqpk,              64, (long)512 * 64, 8, (long)1536 * 512, 64, 512);
  k_packw<<<dim3(8, 1, 48), 256, 0, stream>>>(Wk, wqpk + 512 * 512,  64, (long)512 * 64, 8, (long)1536 * 512, 64, 512);
  k_packw<<<dim3(8, 1, 48), 256, 0, stream>>>(Wv, wqpk + 1024 * 512, 64, (long)512 * 64, 8, (long)1536 * 512, 64, 512);
  k_packw<<<dim3(8, 8, 6), 256, 0, stream>>>(Wo, wopk, 512, (long)512 * 512, 1, (long)512 * 512, 0, 512);
  k_packw<<<dim3(8, 32, 6), 256, 0, stream>>>(W1, w1pk, 2048, (long)512 * 2048, 1, (long)2048 * 512, 0, 512);
  k_packw<<<dim3(32, 8, 6), 256, 0, stream>>>(W2, w2pk, 512, (long)2048 * 512, 1, (long)512 * 2048, 0, 2048);

  k_embed<<<dim3((unsigned)((NTOK * DD) / 256)), dim3(256), 0, stream>>>(code, emb, x);

  for (int l = 0; l < LL; ++l) {
    k_ln<<<dim3(NTOK / 4), 256, 0, stream>>>(x, xn, nullptr, ln1_g + l * DD, ln1_b + l * DD,
                                             nullptr, nullptr, nullptr);
    // QKV: M=8192 N=1536 K=512, linear bf16 out -> 3072 wave-blocks
    k_pgemm<<<dim3(24 * 128), 64, 0, stream>>>(xn, wqpk + (size_t)l * 1536 * 512, nullptr, nullptr,
                                               nullptr, qkv, (int)NTOK, 1536, 512, 0);
    k_attn<<<dim3(BB * HH * (TT / 64)), 256, 0, stream>>>(qkv, lengths, xn);
    // Wo + bias + residual -> x (fp32): N=512 -> 1024 wave-blocks
    k_pgemm<<<dim3(8 * 128), 64, 0, stream>>>(xn, wopk + (size_t)l * 512 * 512, x, bo + l * DD,
                                              x, nullptr, (int)NTOK, 512, 512, 1);
    k_ln<<<dim3(NTOK / 4), 256, 0, stream>>>(x, xn, nullptr, ln2_g + l * DD, ln2_b + l * DD,
                                             nullptr, nullptr, nullptr);
    // W1 + bias + GELU -> h1 (packed bf16): N=2048 -> 4096 wave-blocks
    k_pgemm<<<dim3(32 * 128), 64, 0, stream>>>(xn, w1pk + (size_t)l * 512 * FF4, nullptr, b1 + l * FF4,
                                               nullptr, h1, (int)NTOK, FF4, 512, 2);
    // W2 + bias + residual -> x (fp32): K=2048, N=512 -> 1024 wave-blocks
    k_pgemm<<<dim3(8 * 128), 64, 0, stream>>>(h1, w2pk + (size_t)l * FF4 * 512, x, b2 + l * DD,
                                              x, nullptr, (int)NTOK, 512, 2048, 1);
  }
  k_ln<<<dim3(NTOK / 4), 256, 0, stream>>>(x, nullptr, xf, lnf_g, lnf_b,
                                           attn_w, attn_b, scores);
  k_softw<<<dim3(BB), 256, 0, stream>>>(scores, lengths, wts);
  k_wsum<<<dim3(BB, 16), 256, 0, stream>>>(xf, wts, partial);
  k_head<<<dim3(BB), 64, 0, stream>>>(partial, head_w, head_b, out);
}

// Round 9
// 1547.988 us; speedup vs baseline: 1.1934x; 1.1430x over previous
//
#include <hip/hip_runtime.h>
#include <math.h>

#define TT 1024
#define BB 8
#define DD 512
#define HH 8
#define HSZ 64
#define LL 6
#define FF4 2048

typedef __attribute__((ext_vector_type(8))) short short8;
typedef __attribute__((ext_vector_type(4))) float floatx4;
typedef unsigned short ushort_t;
typedef unsigned int uint_t;

__device__ __forceinline__ ushort_t f2bf(float f) {
  uint_t u = __float_as_uint(f);
  u += 0x7fff + ((u >> 16) & 1);  // RNE
  return (ushort_t)(u >> 16);
}
__device__ __forceinline__ float bf2f(ushort_t h) {
  return __uint_as_float(((uint_t)h) << 16);
}

// Packed MFMA-fragment layout for a [rows x Kd] bf16 matrix:
// tile (r16=row>>4, c32=col>>5); element index =
//   ((r16*(Kd>>5)+c32)<<9) + (((col>>3)&3)*16 + (row&15))*8 + (col&7)
// A wave's fragment (16 rows x 32 cols) is one contiguous 1KB chunk,
// lane i holding bytes [i*16, i*16+16) -> one coalesced global_load_dwordx4.

// ---------------- embed + positional encoding ----------------
__global__ __launch_bounds__(256) void k_embed(const int* __restrict__ code,
                                               const float* __restrict__ emb,
                                               float* __restrict__ x) {
  int idx = blockIdx.x * 256 + threadIdx.x;  // over B*T*D
  int c = idx & (DD - 1);
  int bt = idx >> 9;
  int t = bt & (TT - 1);
  int f = c >> 4, e = c & 15;
  int vv = code[bt * 32 + f];
  int i = c >> 1;
  float freq = expf((float)(2 * i) * (-9.210340371976184f / 512.f));
  float ang = (float)t * freq;
  float pe = (c & 1) ? cosf(ang) : sinf(ang);
  x[idx] = emb[vv * 16 + e] + pe;
}

// ---------------- layernorm: fp32 in -> packed bf16 (or linear fp32 + scores) ----------------
__global__ __launch_bounds__(256) void k_ln(const float* __restrict__ x,
                                            ushort_t* __restrict__ yB,
                                            float* __restrict__ yF,
                                            const float* __restrict__ g,
                                            const float* __restrict__ b,
                                            const float* __restrict__ aw,
                                            const float* __restrict__ ab,
                                            float* __restrict__ scores) {
  int wave = threadIdx.x >> 6, lane = threadIdx.x & 63;
  int row = blockIdx.x * 4 + wave;
  const float* xr = x + (size_t)row * DD;
  float v[8];
  *(float4*)&v[0] = *(const float4*)(xr + lane * 8);
  *(float4*)&v[4] = *(const float4*)(xr + lane * 8 + 4);
  float s = 0.f;
#pragma unroll
  for (int j = 0; j < 8; ++j) s += v[j];
#pragma unroll
  for (int off = 32; off; off >>= 1) s += __shfl_down(s, off, 64);
  float mean = __shfl(s, 0, 64) * (1.f / DD);
  float qv = 0.f;
#pragma unroll
  for (int j = 0; j < 8; ++j) { float d = v[j] - mean; qv += d * d; }
#pragma unroll
  for (int off = 32; off; off >>= 1) qv += __shfl_down(qv, off, 64);
  float rs = rsqrtf(__shfl(qv, 0, 64) * (1.f / DD) + 1e-5f);
  float ov[8];
  float sdot = 0.f;
#pragma unroll
  for (int e = 0; e < 8; ++e) {
    int c = lane * 8 + e;
    ov[e] = (v[e] - mean) * rs * g[c] + b[c];
    if (scores) sdot += ov[e] * aw[c];
  }
  if (yB) {
    short8 o8;
#pragma unroll
    for (int e = 0; e < 8; ++e) o8[e] = (short)f2bf(ov[e]);
    // packed addr: Kd=512, tile=(row>>4, lane>>2), inner=(lane&3)*16+(row&15)
    size_t ad = (((size_t)(row >> 4) * 16 + (lane >> 2)) << 9) + ((lane & 3) * 16 + (row & 15)) * 8;
    *(short8*)(yB + ad) = o8;
  } else {
    float* yr = yF + (size_t)row * DD + lane * 8;
    *(float4*)yr = *(float4*)&ov[0];
    *(float4*)(yr + 4) = *(float4*)&ov[4];
  }
  if (scores) {
#pragma unroll
    for (int off = 32; off; off >>= 1) sdot += __shfl_down(sdot, off, 64);
    if (lane == 0) scores[row] = sdot + ab[0];
  }
}

// ---------------- fp32 weights -> packed bf16 B-operand ----------------
__global__ __launch_bounds__(256) void k_packw(const float* __restrict__ in,
                                               ushort_t* __restrict__ out,
                                               int Nin, long in_ms, int nh,
                                               long os_l, int nblk, int Kout) {
  __shared__ float t4[64][65];
  int mz = blockIdx.z;
  const float* ip = in + (size_t)mz * in_ms;
  ushort_t* op = out + (size_t)(mz / nh) * os_l;
  int nbase = (mz % nh) * nblk + blockIdx.y * 64;
  int k0 = blockIdx.x * 64;
  int cc = threadIdx.x & 63, r0 = threadIdx.x >> 6;
#pragma unroll
  for (int i = 0; i < 16; ++i) {
    int r = r0 * 16 + i;
    t4[r][cc] = ip[(size_t)(k0 + r) * Nin + (nbase - (mz % nh) * nblk) + cc];
  }
  __syncthreads();
#pragma unroll
  for (int half = 0; half < 2; ++half) {
    int c = threadIdx.x + half * 256;
    int joct = c >> 6, nl = c & 63;
    int n = nbase + nl, k = k0 + joct * 8;
    short8 v8;
#pragma unroll
    for (int e = 0; e < 8; ++e) v8[e] = (short)f2bf(t4[joct * 8 + e][nl]);
    size_t ad = (((size_t)(n >> 4) * (Kout >> 5) + (k >> 5)) << 9) + (((k >> 3) & 3) * 16 + (n & 15)) * 8;
    *(short8*)(op + ad) = v8;
  }
}

// ---------------- packed-fragment MFMA GEMM: no barriers, 2-stage reg pipeline ----------------
// MT=4: 64x64 wave tile (QKV/W1); MT=2: 32x64 (Wo/W2, 2 waves/SIMD).
// __launch_bounds__(64,2): 256-VGPR cap so acc(16*MT) + dbuf frags stay live
// and the 4+MT loads per k-step issue as one batch (no compiler load-sinking).
// mode 0: outB linear bf16; mode 1: outF = acc+bias+resid (fp32);
// mode 2 (MT=4 only): outB packed bf16 of gelu(acc+bias).
template <int MT>
__global__ __launch_bounds__(64, 2) void k_pgemm(const ushort_t* __restrict__ Apk,
                                                 const ushort_t* __restrict__ Bpk,
                                                 const float* __restrict__ resid,
                                                 const float* __restrict__ bias,
                                                 float* __restrict__ outF,
                                                 ushort_t* __restrict__ outB,
                                                 int M, int N, int K, int mode) {
  __shared__ ushort_t Cb[MT == 4 ? 64 * 80 : 64];
  const int lane = threadIdx.x;
  const int quad = lane >> 4, l16 = lane & 15;
  const int gx = N >> 6;
  int id = blockIdx.x;
  int bx = (id >> 3) % gx;
  int by = (id / (8 * gx)) * 8 + (id & 7);  // same-row tiles share an XCD
  const int row0 = by * (MT * 16), col0 = bx * 64;
  const int nk = K >> 5;
  const ushort_t* Ab = Apk + (((size_t)(row0 >> 4) * nk) << 9) + lane * 8;
  const ushort_t* Bb = Bpk + (((size_t)(col0 >> 4) * nk) << 9) + lane * 8;
  floatx4 acc[MT][4] = {};
  short8 a0[MT], b0[4], a1[MT], b1[4];
#pragma unroll
  for (int mt = 0; mt < MT; ++mt) a0[mt] = *(const short8*)(Ab + (((size_t)mt * nk) << 9));
#pragma unroll
  for (int nt = 0; nt < 4; ++nt) b0[nt] = *(const short8*)(Bb + (((size_t)nt * nk) << 9));
  for (int kc = 0; kc < nk; kc += 2) {
    // batch-issue loads for step kc+1, then MFMA on step kc
#pragma unroll
    for (int mt = 0; mt < MT; ++mt) a1[mt] = *(const short8*)(Ab + (((size_t)(mt * nk + kc + 1)) << 9));
#pragma unroll
    for (int nt = 0; nt < 4; ++nt) b1[nt] = *(const short8*)(Bb + (((size_t)(nt * nk + kc + 1)) << 9));
#pragma unroll
    for (int mt = 0; mt < MT; ++mt)
#pragma unroll
      for (int nt = 0; nt < 4; ++nt)
        acc[mt][nt] = __builtin_amdgcn_mfma_f32_16x16x32_bf16(a0[mt], b0[nt], acc[mt][nt], 0, 0, 0);
    if (kc + 2 < nk) {
#pragma unroll
      for (int mt = 0; mt < MT; ++mt) a0[mt] = *(const short8*)(Ab + (((size_t)(mt * nk + kc + 2)) << 9));
#pragma unroll
      for (int nt = 0; nt < 4; ++nt) b0[nt] = *(const short8*)(Bb + (((size_t)(nt * nk + kc + 2)) << 9));
    }
#pragma unroll
    for (int mt = 0; mt < MT; ++mt)
#pragma unroll
      for (int nt = 0; nt < 4; ++nt)
        acc[mt][nt] = __builtin_amdgcn_mfma_f32_16x16x32_bf16(a1[mt], b1[nt], acc[mt][nt], 0, 0, 0);
  }

  if (MT == 4 && mode == 2) {
    // gelu(acc+bias) -> per-wave LDS -> packed bf16 (Kd = N of this GEMM)
#pragma unroll
    for (int mt = 0; mt < MT; ++mt)
#pragma unroll
      for (int nt = 0; nt < 4; ++nt) {
        floatx4 a4 = acc[mt][nt];
#pragma unroll
        for (int r = 0; r < 4; ++r) {
          float val = a4[r] + bias[col0 + nt * 16 + l16];
          val = 0.5f * val * (1.f + erff(val * 0.7071067811865475f));
          Cb[(mt * 16 + quad * 4 + r) * 80 + nt * 16 + l16] = f2bf(val);
        }
      }
#pragma unroll
    for (int mt2 = 0; mt2 < 4; ++mt2)
#pragma unroll
      for (int kt2 = 0; kt2 < 2; ++kt2) {
        short8 v8 = *(const short8*)&Cb[(mt2 * 16 + l16) * 80 + kt2 * 32 + quad * 8];
        size_t ad = ((((size_t)(row0 >> 4) + mt2) * (N >> 5) + (col0 >> 5) + kt2) << 9) + lane * 8;
        *(short8*)(outB + ad) = v8;
      }
  } else {
#pragma unroll
    for (int mt = 0; mt < MT; ++mt)
#pragma unroll
      for (int nt = 0; nt < 4; ++nt) {
        floatx4 a4 = acc[mt][nt];
#pragma unroll
        for (int r = 0; r < 4; ++r) {
          int row = row0 + mt * 16 + quad * 4 + r;
          int col = col0 + nt * 16 + l16;
          float val = a4[r];
          if (bias) val += bias[col];
          size_t idx = (size_t)row * N + col;
          if (mode == 1) outF[idx] = val + resid[idx];
          else outB[idx] = f2bf(val);
        }
      }
  }
}

// ---------------- MFMA flash attention (qkv linear bf16 in, packed bf16 out) ----------------
__global__ __launch_bounds__(256) void k_attn(const ushort_t* __restrict__ qkv,
                                              const int* __restrict__ lengths,
                                              ushort_t* __restrict__ o) {
  __shared__ ushort_t Ks[64 * 72];
  __shared__ ushort_t Vt[64 * 72];
  __shared__ ushort_t Ps[4][16 * 80];
  const int tid = threadIdx.x;
  const int w = tid >> 6, lane = tid & 63;
  const int quad = lane >> 4, l16 = lane & 15;
  const int tile = blockIdx.x & 15;
  const int bh = blockIdx.x >> 4;
  const int b = bh >> 3, h = bh & 7;
  const int len = lengths[b];
  const int tqa = tile * 64 + w * 16 + l16;
  const ushort_t* qp = qkv + ((size_t)(b * TT + tqa)) * 1536 + h * HSZ + quad * 8;
  short8 qf0 = *(const short8*)qp;
  short8 qf1 = *(const short8*)(qp + 32);
  floatx4 oacc[4] = {};
  float mrun[4], lrun[4];
#pragma unroll
  for (int r = 0; r < 4; ++r) { mrun[r] = -1e30f; lrun[r] = 0.f; }
  const int skey = tid >> 2, sseg = (tid & 3) << 4;
  const int vkp = (tid & 31) << 1, vds = (tid >> 5) << 3;
  const int nkt = (len + 63) >> 6;
  for (int kt = 0; kt < nkt; ++kt) {
    const int s0 = kt * 64;
    __syncthreads();
    {
      const ushort_t* kp = qkv + ((size_t)(b * TT + s0 + skey)) * 1536 + 512 + h * HSZ + sseg;
      short8 k0 = *(const short8*)kp;
      short8 k1 = *(const short8*)(kp + 8);
      *(short8*)&Ks[skey * 72 + sseg] = k0;
      *(short8*)&Ks[skey * 72 + sseg + 8] = k1;
      const ushort_t* vp0 = qkv + ((size_t)(b * TT + s0 + vkp)) * 1536 + 1024 + h * HSZ + vds;
      short8 v0 = *(const short8*)vp0;
      short8 v1 = *(const short8*)(vp0 + 1536);
#pragma unroll
      for (int i = 0; i < 8; ++i) {
        ushort2 pr;
        pr.x = (ushort_t)v0[i];
        pr.y = (ushort_t)v1[i];
        *(ushort2*)&Vt[(vds + i) * 72 + vkp] = pr;
      }
    }
    __syncthreads();
    floatx4 sacc[4] = {};
#pragma unroll
    for (int nt = 0; nt < 4; ++nt) {
      short8 kf0 = *(const short8*)&Ks[(nt * 16 + l16) * 72 + quad * 8];
      short8 kf1 = *(const short8*)&Ks[(nt * 16 + l16) * 72 + 32 + quad * 8];
      sacc[nt] = __builtin_amdgcn_mfma_f32_16x16x32_bf16(qf0, kf0, sacc[nt], 0, 0, 0);
      sacc[nt] = __builtin_amdgcn_mfma_f32_16x16x32_bf16(qf1, kf1, sacc[nt], 0, 0, 0);
    }
    float p[4][4], mx[4];
#pragma unroll
    for (int r = 0; r < 4; ++r) {
      float m = -1e30f;
#pragma unroll
      for (int nt = 0; nt < 4; ++nt) {
        float s = (s0 + nt * 16 + l16 < len) ? sacc[nt][r] * 0.125f : -1e30f;
        p[nt][r] = s;
        m = fmaxf(m, s);
      }
      mx[r] = m;
    }
#pragma unroll
    for (int off = 1; off < 16; off <<= 1) {
#pragma unroll
      for (int r = 0; r < 4; ++r) mx[r] = fmaxf(mx[r], __shfl_xor(mx[r], off, 64));
    }
    float corr[4], rs[4];
#pragma unroll
    for (int r = 0; r < 4; ++r) {
      float mnew = fmaxf(mrun[r], mx[r]);
      corr[r] = __expf(mrun[r] - mnew);
      mrun[r] = mnew;
      float s = 0.f;
#pragma unroll
      for (int nt = 0; nt < 4; ++nt) {
        float e = __expf(p[nt][r] - mnew);
        p[nt][r] = e;
        s += e;
      }
      rs[r] = s;
    }
#pragma unroll
    for (int off = 1; off < 16; off <<= 1) {
#pragma unroll
      for (int r = 0; r < 4; ++r) rs[r] += __shfl_xor(rs[r], off, 64);
    }
#pragma unroll
    for (int r = 0; r < 4; ++r) {
      lrun[r] = lrun[r] * corr[r] + rs[r];
#pragma unroll
      for (int nt = 0; nt < 4; ++nt) {
        oacc[nt][r] *= corr[r];
        Ps[w][(quad * 4 + r) * 80 + nt * 16 + l16] = f2bf(p[nt][r]);
      }
    }
    short8 pf0 = *(const short8*)&Ps[w][l16 * 80 + quad * 8];
    short8 pf1 = *(const short8*)&Ps[w][l16 * 80 + 32 + quad * 8];
#pragma unroll
    for (int nt = 0; nt < 4; ++nt) {
      short8 vf0 = *(const short8*)&Vt[(nt * 16 + l16) * 72 + quad * 8];
      short8 vf1 = *(const short8*)&Vt[(nt * 16 + l16) * 72 + 32 + quad * 8];
      oacc[nt] = __builtin_amdgcn_mfma_f32_16x16x32_bf16(pf0, vf0, oacc[nt], 0, 0, 0);
      oacc[nt] = __builtin_amdgcn_mfma_f32_16x16x32_bf16(pf1, vf1, oacc[nt], 0, 0, 0);
    }
  }
  // epilogue: per-wave LDS shuffle into packed-A layout (Kd=512)
#pragma unroll
  for (int r = 0; r < 4; ++r) {
    int t = tile * 64 + w * 16 + quad * 4 + r;
    float inv = (t < len) ? 1.f / lrun[r] : 0.f;  // row mask
#pragma unroll
    for (int nt = 0; nt < 4; ++nt)
      Ps[w][(quad * 4 + r) * 80 + nt * 16 + l16] = f2bf(oacc[nt][r] * inv);
  }
  const int mtile = b * 64 + tile * 4 + w;
#pragma unroll
  for (int kt2 = 0; kt2 < 2; ++kt2) {
    short8 v8 = *(const short8*)&Ps[w][l16 * 80 + kt2 * 32 + quad * 8];
    size_t ad = (((size_t)mtile * 16 + h * 2 + kt2) << 9) + lane * 8;
    *(short8*)(o + ad) = v8;
  }
}

// ---------------- pool softmax: scores -> weights (per batch) ----------------
__global__ __launch_bounds__(256) void k_softw(const float* __restrict__ scores,
                                               const int* __restrict__ lengths,
                                               float* __restrict__ wts) {
  __shared__ float red[8];
  int tid = threadIdx.x, b = blockIdx.x;
  int len = lengths[b];
  const float* sb = scores + b * TT;
  float m = -1e30f;
  for (int t = tid; t < len; t += 256) m = fmaxf(m, sb[t]);
#pragma unroll
  for (int off = 32; off; off >>= 1) m = fmaxf(m, __shfl_down(m, off, 64));
  if ((tid & 63) == 0) red[tid >> 6] = m;
  __syncthreads();
  m = fmaxf(fmaxf(red[0], red[1]), fmaxf(red[2], red[3]));
  float ssum = 0.f;
  for (int t = tid; t < len; t += 256) ssum += __expf(sb[t] - m);
#pragma unroll
  for (int off = 32; off; off >>= 1) ssum += __shfl_down(ssum, off, 64);
  if ((tid & 63) == 0) red[4 + (tid >> 6)] = ssum;
  __syncthreads();
  float inv = 1.f / (red[4] + red[5] + red[6] + red[7]);
  for (int t = tid; t < TT; t += 256)
    wts[b * TT + t] = (t < len) ? __expf(sb[t] - m) * inv : 0.f;
}

// ---------------- weighted sum partials: grid (B, 16), 64 rows each ----------------
__global__ __launch_bounds__(256) void k_wsum(const float* __restrict__ xf,
                                              const float* __restrict__ wts,
                                              float* __restrict__ partial) {
  int b = blockIdx.x, c = blockIdx.y, tid = threadIdx.x;
  const float* xb = xf + ((size_t)b * TT + c * 64) * DD;
  const float* wb = wts + b * TT + c * 64;
  float a0 = 0.f, a1 = 0.f;
  for (int t = 0; t < 64; ++t) {
    float wv = wb[t];
    a0 += wv * xb[(size_t)t * DD + tid];
    a1 += wv * xb[(size_t)t * DD + tid + 256];
  }
  float* pp = partial + ((size_t)b * 16 + c) * DD;
  pp[tid] = a0;
  pp[tid + 256] = a1;
}

// ---------------- classification head (reduces the 16 partials) ----------------
__global__ __launch_bounds__(64) void k_head(const float* __restrict__ partial,
                                             const float* __restrict__ head_w,
                                             const float* __restrict__ head_b,
                                             float* __restrict__ out) {
  __shared__ float ssum[DD];
  int b = blockIdx.x, tid = threadIdx.x;
  for (int d = tid; d < DD; d += 64) {
    float s = 0.f;
#pragma unroll
    for (int c = 0; c < 16; ++c) s += partial[((size_t)b * 16 + c) * DD + d];
    ssum[d] = s;
  }
  __syncthreads();
  if (tid < 49) {
    float s = head_b[tid];
    for (int d = 0; d < DD; ++d) s += ssum[d] * head_w[d * 49 + tid];
    out[b * 49 + tid] = s;
  }
}

extern "C" void kernel_launch(void* const* d_in, const int* in_sizes, int n_in,
                              void* d_out, int out_size, void* d_ws, size_t ws_size,
                              hipStream_t stream) {
  const int* code = (const int*)d_in[0];
  const int* lengths = (const int*)d_in[1];
  const float* emb = (const float*)d_in[2];
  const float* Wq = (const float*)d_in[3];
  const float* Wk = (const float*)d_in[4];
  const float* Wv = (const float*)d_in[5];
  const float* Wo = (const float*)d_in[6];
  const float* bo = (const float*)d_in[7];
  const float* W1 = (const float*)d_in[8];
  const float* b1 = (const float*)d_in[9];
  const float* W2 = (const float*)d_in[10];
  const float* b2 = (const float*)d_in[11];
  const float* ln1_g = (const float*)d_in[12];
  const float* ln1_b = (const float*)d_in[13];
  const float* ln2_g = (const float*)d_in[14];
  const float* ln2_b = (const float*)d_in[15];
  const float* lnf_g = (const float*)d_in[16];
  const float* lnf_b = (const float*)d_in[17];
  const float* attn_w = (const float*)d_in[18];
  const float* attn_b = (const float*)d_in[19];
  const float* head_w = (const float*)d_in[20];
  const float* head_b = (const float*)d_in[21];
  float* out = (float*)d_out;

  const size_t NTOK = (size_t)BB * TT;  // 8192
  float* x = (float*)d_ws;                       // 8192*512 fp32
  ushort_t* xn = (ushort_t*)(x + NTOK * DD);     // 8192*512 bf16 (packed)
  ushort_t* un = xn + NTOK * DD;                 // union: qkv | h1 | xf
  ushort_t* qkv = un;                            // linear bf16
  ushort_t* h1 = un;                             // packed bf16
  float* xf = (float*)un;
  ushort_t* wqpk = un + (size_t)NTOK * FF4;      // packed 6x 1536x512
  ushort_t* wopk = wqpk + (size_t)LL * 1536 * 512;
  ushort_t* w1pk = wopk + (size_t)LL * 512 * 512;
  ushort_t* w2pk = w1pk + (size_t)LL * 512 * FF4;
  float* scores = (float*)(w2pk + (size_t)LL * FF4 * 512);  // 8192
  float* wts = scores + NTOK;                               // 8192
  float* partial = wts + NTOK;                              // 8*16*512

  // weight packing (fp32 [k][n] -> packed bf16 fragments)
  k_packw<<<dim3(8, 1, 48), 256, 0, stream>>>(Wq, wqpk,              64, (long)512 * 64, 8, (long)1536 * 512, 64, 512);
  k_packw<<<dim3(8, 1, 48), 256, 0, stream>>>(Wk, wqpk + 512 * 512,  64, (long)512 * 64, 8, (long)1536 * 512, 64, 512);
  k_packw<<<dim3(8, 1, 48), 256, 0, stream>>>(Wv, wqpk + 1024 * 512, 64, (long)512 * 64, 8, (long)1536 * 512, 64, 512);
  k_packw<<<dim3(8, 8, 6), 256, 0, stream>>>(Wo, wopk, 512, (long)512 * 512, 1, (long)512 * 512, 0, 512);
  k_packw<<<dim3(8, 32, 6), 256, 0, stream>>>(W1, w1pk, 2048, (long)512 * 2048, 1, (long)2048 * 512, 0, 512);
  k_packw<<<dim3(32, 8, 6), 256, 0, stream>>>(W2, w2pk, 512, (long)2048 * 512, 1, (long)512 * 2048, 0, 2048);

  k_embed<<<dim3((unsigned)((NTOK * DD) / 256)), dim3(256), 0, stream>>>(code, emb, x);

  for (int l = 0; l < LL; ++l) {
    k_ln<<<dim3(NTOK / 4), 256, 0, stream>>>(x, xn, nullptr, ln1_g + l * DD, ln1_b + l * DD,
                                             nullptr, nullptr, nullptr);
    // QKV: M=8192 N=1536 K=512, 64x64 tiles -> 3072 waves (3/SIMD)
    k_pgemm<4><<<dim3(24 * 128), 64, 0, stream>>>(xn, wqpk + (size_t)l * 1536 * 512, nullptr, nullptr,
                                                  nullptr, qkv, (int)NTOK, 1536, 512, 0);
    k_attn<<<dim3(BB * HH * (TT / 64)), 256, 0, stream>>>(qkv, lengths, xn);
    // Wo + bias + residual -> x (fp32): 32x64 tiles -> 2048 waves (2/SIMD)
    k_pgemm<2><<<dim3(8 * 256), 64, 0, stream>>>(xn, wopk + (size_t)l * 512 * 512, x, bo + l * DD,
                                                 x, nullptr, (int)NTOK, 512, 512, 1);
    k_ln<<<dim3(NTOK / 4), 256, 0, stream>>>(x, xn, nullptr, ln2_g + l * DD, ln2_b + l * DD,
                                             nullptr, nullptr, nullptr);
    // W1 + bias + GELU -> h1 (packed bf16): 64x64 tiles -> 4096 waves
    k_pgemm<4><<<dim3(32 * 128), 64, 0, stream>>>(xn, w1pk + (size_t)l * 512 * FF4, nullptr, b1 + l * FF4,
                                                  nullptr, h1, (int)NTOK, FF4, 512, 2);
    // W2 + bias + residual -> x (fp32): K=2048, 32x64 tiles -> 2048 waves (2/SIMD)
    k_pgemm<2><<<dim3(8 * 256), 64, 0, stream>>>(h1, w2pk + (size_t)l * FF4 * 512, x, b2 + l * DD,
                                                 x, nullptr, (int)NTOK, 512, 2048, 1);
  }
  k_ln<<<dim3(NTOK / 4), 256, 0, stream>>>(x, nullptr, xf, lnf_g, lnf_b,
                                           attn_w, attn_b, scores);
  k_softw<<<dim3(BB), 256, 0, stream>>>(scores, lengths, wts);
  k_wsum<<<dim3(BB, 16), 256, 0, stream>>>(xf, wts, partial);
  k_head<<<dim3(BB), 64, 0, stream>>>(partial, head_w, head_b, out);
}

// Round 10
// 1435.313 us; speedup vs baseline: 1.2871x; 1.0785x over previous
//
#include <hip/hip_runtime.h>
#include <math.h>

#define TT 1024
#define BB 8
#define DD 512
#define HH 8
#define HSZ 64
#define LL 6
#define FF4 2048

typedef __attribute__((ext_vector_type(8))) short short8;
typedef __attribute__((ext_vector_type(4))) float floatx4;
typedef unsigned short ushort_t;
typedef unsigned int uint_t;

__device__ __forceinline__ ushort_t f2bf(float f) {
  uint_t u = __float_as_uint(f);
  u += 0x7fff + ((u >> 16) & 1);  // RNE
  return (ushort_t)(u >> 16);
}
__device__ __forceinline__ float bf2f(ushort_t h) {
  return __uint_as_float(((uint_t)h) << 16);
}

// Packed MFMA-fragment layout for a [rows x Kd] bf16 matrix:
// tile (r16=row>>4, c32=col>>5); element index =
//   ((r16*(Kd>>5)+c32)<<9) + (((col>>3)&3)*16 + (row&15))*8 + (col&7)
// A wave's fragment (16 rows x 32 cols) is one contiguous 1KB chunk,
// lane i holding bytes [i*16, i*16+16) -> one coalesced global_load_dwordx4.

// ---------------- embed + positional encoding ----------------
__global__ __launch_bounds__(256) void k_embed(const int* __restrict__ code,
                                               const float* __restrict__ emb,
                                               float* __restrict__ x) {
  int idx = blockIdx.x * 256 + threadIdx.x;  // over B*T*D
  int c = idx & (DD - 1);
  int bt = idx >> 9;
  int t = bt & (TT - 1);
  int f = c >> 4, e = c & 15;
  int vv = code[bt * 32 + f];
  int i = c >> 1;
  float freq = expf((float)(2 * i) * (-9.210340371976184f / 512.f));
  float ang = (float)t * freq;
  float pe = (c & 1) ? cosf(ang) : sinf(ang);
  x[idx] = emb[vv * 16 + e] + pe;
}

// ---------------- layernorm: fp32 in -> packed bf16 (or linear fp32 + scores) ----------------
__global__ __launch_bounds__(256) void k_ln(const float* __restrict__ x,
                                            ushort_t* __restrict__ yB,
                                            float* __restrict__ yF,
                                            const float* __restrict__ g,
                                            const float* __restrict__ b,
                                            const float* __restrict__ aw,
                                            const float* __restrict__ ab,
                                            float* __restrict__ scores) {
  int wave = threadIdx.x >> 6, lane = threadIdx.x & 63;
  int row = blockIdx.x * 4 + wave;
  const float* xr = x + (size_t)row * DD;
  float v[8];
  *(float4*)&v[0] = *(const float4*)(xr + lane * 8);
  *(float4*)&v[4] = *(const float4*)(xr + lane * 8 + 4);
  float s = 0.f;
#pragma unroll
  for (int j = 0; j < 8; ++j) s += v[j];
#pragma unroll
  for (int off = 32; off; off >>= 1) s += __shfl_down(s, off, 64);
  float mean = __shfl(s, 0, 64) * (1.f / DD);
  float qv = 0.f;
#pragma unroll
  for (int j = 0; j < 8; ++j) { float d = v[j] - mean; qv += d * d; }
#pragma unroll
  for (int off = 32; off; off >>= 1) qv += __shfl_down(qv, off, 64);
  float rs = rsqrtf(__shfl(qv, 0, 64) * (1.f / DD) + 1e-5f);
  float ov[8];
  float sdot = 0.f;
#pragma unroll
  for (int e = 0; e < 8; ++e) {
    int c = lane * 8 + e;
    ov[e] = (v[e] - mean) * rs * g[c] + b[c];
    if (scores) sdot += ov[e] * aw[c];
  }
  if (yB) {
    short8 o8;
#pragma unroll
    for (int e = 0; e < 8; ++e) o8[e] = (short)f2bf(ov[e]);
    size_t ad = (((size_t)(row >> 4) * 16 + (lane >> 2)) << 9) + ((lane & 3) * 16 + (row & 15)) * 8;
    *(short8*)(yB + ad) = o8;
  } else {
    float* yr = yF + (size_t)row * DD + lane * 8;
    *(float4*)yr = *(float4*)&ov[0];
    *(float4*)(yr + 4) = *(float4*)&ov[4];
  }
  if (scores) {
#pragma unroll
    for (int off = 32; off; off >>= 1) sdot += __shfl_down(sdot, off, 64);
    if (lane == 0) scores[row] = sdot + ab[0];
  }
}

// ---------------- fp32 weights -> packed bf16 B-operand ----------------
__global__ __launch_bounds__(256) void k_packw(const float* __restrict__ in,
                                               ushort_t* __restrict__ out,
                                               int Nin, long in_ms, int nh,
                                               long os_l, int nblk, int Kout) {
  __shared__ float t4[64][65];
  int mz = blockIdx.z;
  const float* ip = in + (size_t)mz * in_ms;
  ushort_t* op = out + (size_t)(mz / nh) * os_l;
  int nbase = (mz % nh) * nblk + blockIdx.y * 64;
  int k0 = blockIdx.x * 64;
  int cc = threadIdx.x & 63, r0 = threadIdx.x >> 6;
#pragma unroll
  for (int i = 0; i < 16; ++i) {
    int r = r0 * 16 + i;
    t4[r][cc] = ip[(size_t)(k0 + r) * Nin + (nbase - (mz % nh) * nblk) + cc];
  }
  __syncthreads();
#pragma unroll
  for (int half = 0; half < 2; ++half) {
    int c = threadIdx.x + half * 256;
    int joct = c >> 6, nl = c & 63;
    int n = nbase + nl, k = k0 + joct * 8;
    short8 v8;
#pragma unroll
    for (int e = 0; e < 8; ++e) v8[e] = (short)f2bf(t4[joct * 8 + e][nl]);
    size_t ad = (((size_t)(n >> 4) * (Kout >> 5) + (k >> 5)) << 9) + (((k >> 3) & 3) * 16 + (n & 15)) * 8;
    *(short8*)(op + ad) = v8;
  }
}

// ---------------- packed-fragment MFMA GEMM: no barriers, 2-stage reg pipeline ----------------
// MT=4: 64x64 wave tile (QKV/W1), launch_bounds(64,3) -> <=170 VGPR, 3 waves/SIMD.
// MT=2: 32x64 (Wo/W2), launch_bounds(64,2).
// mode 0: outB linear bf16; mode 3: same + q-part (col<512) scaled by 0.125;
// mode 1: outF = acc+bias+resid (fp32); mode 2 (MT=4): outB packed bf16 gelu(acc+bias).
template <int MT>
__global__ __launch_bounds__(64, (MT == 4) ? 3 : 2) void k_pgemm(const ushort_t* __restrict__ Apk,
                                                                 const ushort_t* __restrict__ Bpk,
                                                                 const float* __restrict__ resid,
                                                                 const float* __restrict__ bias,
                                                                 float* __restrict__ outF,
                                                                 ushort_t* __restrict__ outB,
                                                                 int M, int N, int K, int mode) {
  __shared__ ushort_t Cb[MT == 4 ? 64 * 80 : 64];
  const int lane = threadIdx.x;
  const int quad = lane >> 4, l16 = lane & 15;
  const int gx = N >> 6;
  int id = blockIdx.x;
  int bx = (id >> 3) % gx;
  int by = (id / (8 * gx)) * 8 + (id & 7);  // same-row tiles share an XCD
  const int row0 = by * (MT * 16), col0 = bx * 64;
  const int nk = K >> 5;
  const ushort_t* Ab = Apk + (((size_t)(row0 >> 4) * nk) << 9) + lane * 8;
  const ushort_t* Bb = Bpk + (((size_t)(col0 >> 4) * nk) << 9) + lane * 8;
  floatx4 acc[MT][4] = {};
  short8 a0[MT], b0[4], a1[MT], b1[4];
#pragma unroll
  for (int mt = 0; mt < MT; ++mt) a0[mt] = *(const short8*)(Ab + (((size_t)mt * nk) << 9));
#pragma unroll
  for (int nt = 0; nt < 4; ++nt) b0[nt] = *(const short8*)(Bb + (((size_t)nt * nk) << 9));
  for (int kc = 0; kc < nk; kc += 2) {
    // batch-issue loads for step kc+1, then MFMA on step kc
#pragma unroll
    for (int mt = 0; mt < MT; ++mt) a1[mt] = *(const short8*)(Ab + (((size_t)(mt * nk + kc + 1)) << 9));
#pragma unroll
    for (int nt = 0; nt < 4; ++nt) b1[nt] = *(const short8*)(Bb + (((size_t)(nt * nk + kc + 1)) << 9));
#pragma unroll
    for (int mt = 0; mt < MT; ++mt)
#pragma unroll
      for (int nt = 0; nt < 4; ++nt)
        acc[mt][nt] = __builtin_amdgcn_mfma_f32_16x16x32_bf16(a0[mt], b0[nt], acc[mt][nt], 0, 0, 0);
    if (kc + 2 < nk) {
#pragma unroll
      for (int mt = 0; mt < MT; ++mt) a0[mt] = *(const short8*)(Ab + (((size_t)(mt * nk + kc + 2)) << 9));
#pragma unroll
      for (int nt = 0; nt < 4; ++nt) b0[nt] = *(const short8*)(Bb + (((size_t)(nt * nk + kc + 2)) << 9));
    }
#pragma unroll
    for (int mt = 0; mt < MT; ++mt)
#pragma unroll
      for (int nt = 0; nt < 4; ++nt)
        acc[mt][nt] = __builtin_amdgcn_mfma_f32_16x16x32_bf16(a1[mt], b1[nt], acc[mt][nt], 0, 0, 0);
  }

  if (MT == 4 && mode == 2) {
    // gelu(acc+bias) -> per-wave LDS -> packed bf16 (Kd = N of this GEMM)
#pragma unroll
    for (int mt = 0; mt < MT; ++mt)
#pragma unroll
      for (int nt = 0; nt < 4; ++nt) {
        floatx4 a4 = acc[mt][nt];
#pragma unroll
        for (int r = 0; r < 4; ++r) {
          float val = a4[r] + bias[col0 + nt * 16 + l16];
          val = 0.5f * val * (1.f + erff(val * 0.7071067811865475f));
          Cb[(mt * 16 + quad * 4 + r) * 80 + nt * 16 + l16] = f2bf(val);
        }
      }
#pragma unroll
    for (int mt2 = 0; mt2 < 4; ++mt2)
#pragma unroll
      for (int kt2 = 0; kt2 < 2; ++kt2) {
        short8 v8 = *(const short8*)&Cb[(mt2 * 16 + l16) * 80 + kt2 * 32 + quad * 8];
        size_t ad = ((((size_t)(row0 >> 4) + mt2) * (N >> 5) + (col0 >> 5) + kt2) << 9) + lane * 8;
        *(short8*)(outB + ad) = v8;
      }
  } else {
    const float qscale = (mode == 3 && col0 < 512) ? 0.125f : 1.0f;  // pre-scale Q for attn
#pragma unroll
    for (int mt = 0; mt < MT; ++mt)
#pragma unroll
      for (int nt = 0; nt < 4; ++nt) {
        floatx4 a4 = acc[mt][nt];
#pragma unroll
        for (int r = 0; r < 4; ++r) {
          int row = row0 + mt * 16 + quad * 4 + r;
          int col = col0 + nt * 16 + l16;
          float val = a4[r];
          if (bias) val += bias[col];
          size_t idx = (size_t)row * N + col;
          if (mode == 1) outF[idx] = val + resid[idx];
          else outB[idx] = f2bf(val * qscale);
        }
      }
  }
}

// ---------------- MFMA flash attention, fixed-max softmax ----------------
// Q pre-scaled by 1/8 in QKV epilogue; post-LN scores are O(1) so exp(s) is
// safe in fp32 without a running max. Row-sum deferred: per-lane partials
// across all K-tiles, one 4-round shuffle reduction at the end.
__global__ __launch_bounds__(256) void k_attn(const ushort_t* __restrict__ qkv,
                                              const int* __restrict__ lengths,
                                              ushort_t* __restrict__ o) {
  __shared__ ushort_t Ks[64 * 72];
  __shared__ ushort_t Vt[64 * 72];
  __shared__ ushort_t Ps[4][16 * 72];  // stride 72: 2-way banks only (m136-free)
  const int tid = threadIdx.x;
  const int w = tid >> 6, lane = tid & 63;
  const int quad = lane >> 4, l16 = lane & 15;
  const int tile = blockIdx.x & 15;
  const int bh = blockIdx.x >> 4;
  const int b = bh >> 3, h = bh & 7;
  const int len = lengths[b];
  const int tqa = tile * 64 + w * 16 + l16;
  const ushort_t* qp = qkv + ((size_t)(b * TT + tqa)) * 1536 + h * HSZ + quad * 8;
  short8 qf0 = *(const short8*)qp;
  short8 qf1 = *(const short8*)(qp + 32);
  floatx4 oacc[4] = {};
  float lsum[4] = {0.f, 0.f, 0.f, 0.f};
  const int skey = tid >> 2, sseg = (tid & 3) << 4;
  const int vkp = (tid & 31) << 1, vds = (tid >> 5) << 3;
  const int nkt = (len + 63) >> 6;
  for (int kt = 0; kt < nkt; ++kt) {
    const int s0 = kt * 64;
    __syncthreads();
    {
      const ushort_t* kp = qkv + ((size_t)(b * TT + s0 + skey)) * 1536 + 512 + h * HSZ + sseg;
      short8 k0 = *(const short8*)kp;
      short8 k1 = *(const short8*)(kp + 8);
      *(short8*)&Ks[skey * 72 + sseg] = k0;
      *(short8*)&Ks[skey * 72 + sseg + 8] = k1;
      const ushort_t* vp0 = qkv + ((size_t)(b * TT + s0 + vkp)) * 1536 + 1024 + h * HSZ + vds;
      short8 v0 = *(const short8*)vp0;
      short8 v1 = *(const short8*)(vp0 + 1536);
#pragma unroll
      for (int i = 0; i < 8; ++i) {
        ushort2 pr;
        pr.x = (ushort_t)v0[i];
        pr.y = (ushort_t)v1[i];
        *(ushort2*)&Vt[(vds + i) * 72 + vkp] = pr;
      }
    }
    __syncthreads();
    floatx4 sacc[4] = {};
#pragma unroll
    for (int nt = 0; nt < 4; ++nt) {
      short8 kf0 = *(const short8*)&Ks[(nt * 16 + l16) * 72 + quad * 8];
      short8 kf1 = *(const short8*)&Ks[(nt * 16 + l16) * 72 + 32 + quad * 8];
      sacc[nt] = __builtin_amdgcn_mfma_f32_16x16x32_bf16(qf0, kf0, sacc[nt], 0, 0, 0);
      sacc[nt] = __builtin_amdgcn_mfma_f32_16x16x32_bf16(qf1, kf1, sacc[nt], 0, 0, 0);
    }
    // p = exp(score); mask only the tail tile (wave-uniform branch)
    float p[4][4];
    if (kt == nkt - 1) {
#pragma unroll
      for (int nt = 0; nt < 4; ++nt) {
        bool valid = (s0 + nt * 16 + l16 < len);
#pragma unroll
        for (int r = 0; r < 4; ++r) p[nt][r] = valid ? __expf(sacc[nt][r]) : 0.f;
      }
    } else {
#pragma unroll
      for (int nt = 0; nt < 4; ++nt)
#pragma unroll
        for (int r = 0; r < 4; ++r) p[nt][r] = __expf(sacc[nt][r]);
    }
#pragma unroll
    for (int r = 0; r < 4; ++r)
#pragma unroll
      for (int nt = 0; nt < 4; ++nt) {
        lsum[r] += p[nt][r];
        Ps[w][(quad * 4 + r) * 72 + nt * 16 + l16] = f2bf(p[nt][r]);
      }
    short8 pf0 = *(const short8*)&Ps[w][l16 * 72 + quad * 8];
    short8 pf1 = *(const short8*)&Ps[w][l16 * 72 + 32 + quad * 8];
#pragma unroll
    for (int nt = 0; nt < 4; ++nt) {
      short8 vf0 = *(const short8*)&Vt[(nt * 16 + l16) * 72 + quad * 8];
      short8 vf1 = *(const short8*)&Vt[(nt * 16 + l16) * 72 + 32 + quad * 8];
      oacc[nt] = __builtin_amdgcn_mfma_f32_16x16x32_bf16(pf0, vf0, oacc[nt], 0, 0, 0);
      oacc[nt] = __builtin_amdgcn_mfma_f32_16x16x32_bf16(pf1, vf1, oacc[nt], 0, 0, 0);
    }
  }
  // one deferred row-sum reduction across the 16 key-lanes
#pragma unroll
  for (int off = 1; off < 16; off <<= 1) {
#pragma unroll
    for (int r = 0; r < 4; ++r) lsum[r] += __shfl_xor(lsum[r], off, 64);
  }
  // epilogue: per-wave LDS shuffle into packed-A layout (Kd=512)
#pragma unroll
  for (int r = 0; r < 4; ++r) {
    int t = tile * 64 + w * 16 + quad * 4 + r;
    float inv = (t < len) ? 1.f / lsum[r] : 0.f;  // row mask
#pragma unroll
    for (int nt = 0; nt < 4; ++nt)
      Ps[w][(quad * 4 + r) * 72 + nt * 16 + l16] = f2bf(oacc[nt][r] * inv);
  }
  const int mtile = b * 64 + tile * 4 + w;
#pragma unroll
  for (int kt2 = 0; kt2 < 2; ++kt2) {
    short8 v8 = *(const short8*)&Ps[w][l16 * 72 + kt2 * 32 + quad * 8];
    size_t ad = (((size_t)mtile * 16 + h * 2 + kt2) << 9) + lane * 8;
    *(short8*)(o + ad) = v8;
  }
}

// ---------------- pool softmax: scores -> weights (per batch) ----------------
__global__ __launch_bounds__(256) void k_softw(const float* __restrict__ scores,
                                               const int* __restrict__ lengths,
                                               float* __restrict__ wts) {
  __shared__ float red[8];
  int tid = threadIdx.x, b = blockIdx.x;
  int len = lengths[b];
  const float* sb = scores + b * TT;
  float m = -1e30f;
  for (int t = tid; t < len; t += 256) m = fmaxf(m, sb[t]);
#pragma unroll
  for (int off = 32; off; off >>= 1) m = fmaxf(m, __shfl_down(m, off, 64));
  if ((tid & 63) == 0) red[tid >> 6] = m;
  __syncthreads();
  m = fmaxf(fmaxf(red[0], red[1]), fmaxf(red[2], red[3]));
  float ssum = 0.f;
  for (int t = tid; t < len; t += 256) ssum += __expf(sb[t] - m);
#pragma unroll
  for (int off = 32; off; off >>= 1) ssum += __shfl_down(ssum, off, 64);
  if ((tid & 63) == 0) red[4 + (tid >> 6)] = ssum;
  __syncthreads();
  float inv = 1.f / (red[4] + red[5] + red[6] + red[7]);
  for (int t = tid; t < TT; t += 256)
    wts[b * TT + t] = (t < len) ? __expf(sb[t] - m) * inv : 0.f;
}

// ---------------- weighted sum partials: grid (B, 16), 64 rows each ----------------
__global__ __launch_bounds__(256) void k_wsum(const float* __restrict__ xf,
                                              const float* __restrict__ wts,
                                              float* __restrict__ partial) {
  int b = blockIdx.x, c = blockIdx.y, tid = threadIdx.x;
  const float* xb = xf + ((size_t)b * TT + c * 64) * DD;
  const float* wb = wts + b * TT + c * 64;
  float a0 = 0.f, a1 = 0.f;
  for (int t = 0; t < 64; ++t) {
    float wv = wb[t];
    a0 += wv * xb[(size_t)t * DD + tid];
    a1 += wv * xb[(size_t)t * DD + tid + 256];
  }
  float* pp = partial + ((size_t)b * 16 + c) * DD;
  pp[tid] = a0;
  pp[tid + 256] = a1;
}

// ---------------- classification head (reduces the 16 partials) ----------------
__global__ __launch_bounds__(64) void k_head(const float* __restrict__ partial,
                                             const float* __restrict__ head_w,
                                             const float* __restrict__ head_b,
                                             float* __restrict__ out) {
  __shared__ float ssum[DD];
  int b = blockIdx.x, tid = threadIdx.x;
  for (int d = tid; d < DD; d += 64) {
    float s = 0.f;
#pragma unroll
    for (int c = 0; c < 16; ++c) s += partial[((size_t)b * 16 + c) * DD + d];
    ssum[d] = s;
  }
  __syncthreads();
  if (tid < 49) {
    float s = head_b[tid];
    for (int d = 0; d < DD; ++d) s += ssum[d] * head_w[d * 49 + tid];
    out[b * 49 + tid] = s;
  }
}

extern "C" void kernel_launch(void* const* d_in, const int* in_sizes, int n_in,
                              void* d_out, int out_size, void* d_ws, size_t ws_size,
                              hipStream_t stream) {
  const int* code = (const int*)d_in[0];
  const int* lengths = (const int*)d_in[1];
  const float* emb = (const float*)d_in[2];
  const float* Wq = (const float*)d_in[3];
  const float* Wk = (const float*)d_in[4];
  const float* Wv = (const float*)d_in[5];
  const float* Wo = (const float*)d_in[6];
  const float* bo = (const float*)d_in[7];
  const float* W1 = (const float*)d_in[8];
  const float* b1 = (const float*)d_in[9];
  const float* W2 = (const float*)d_in[10];
  const float* b2 = (const float*)d_in[11];
  const float* ln1_g = (const float*)d_in[12];
  const float* ln1_b = (const float*)d_in[13];
  const float* ln2_g = (const float*)d_in[14];
  const float* ln2_b = (const float*)d_in[15];
  const float* lnf_g = (const float*)d_in[16];
  const float* lnf_b = (const float*)d_in[17];
  const float* attn_w = (const float*)d_in[18];
  const float* attn_b = (const float*)d_in[19];
  const float* head_w = (const float*)d_in[20];
  const float* head_b = (const float*)d_in[21];
  float* out = (float*)d_out;

  const size_t NTOK = (size_t)BB * TT;  // 8192
  float* x = (float*)d_ws;                       // 8192*512 fp32
  ushort_t* xn = (ushort_t*)(x + NTOK * DD);     // 8192*512 bf16 (packed)
  ushort_t* un = xn + NTOK * DD;                 // union: qkv | h1 | xf
  ushort_t* qkv = un;                            // linear bf16
  ushort_t* h1 = un;                             // packed bf16
  float* xf = (float*)un;
  ushort_t* wqpk = un + (size_t)NTOK * FF4;      // packed 6x 1536x512
  ushort_t* wopk = wqpk + (size_t)LL * 1536 * 512;
  ushort_t* w1pk = wopk + (size_t)LL * 512 * 512;
  ushort_t* w2pk = w1pk + (size_t)LL * 512 * FF4;
  float* scores = (float*)(w2pk + (size_t)LL * FF4 * 512);  // 8192
  float* wts = scores + NTOK;                               // 8192
  float* partial = wts + NTOK;                              // 8*16*512

  // weight packing (fp32 [k][n] -> packed bf16 fragments)
  k_packw<<<dim3(8, 1, 48), 256, 0, stream>>>(Wq, wqpk,              64, (long)512 * 64, 8, (long)1536 * 512, 64, 512);
  k_packw<<<dim3(8, 1, 48), 256, 0, stream>>>(Wk, wqpk + 512 * 512,  64, (long)512 * 64, 8, (long)1536 * 512, 64, 512);
  k_packw<<<dim3(8, 1, 48), 256, 0, stream>>>(Wv, wqpk + 1024 * 512, 64, (long)512 * 64, 8, (long)1536 * 512, 64, 512);
  k_packw<<<dim3(8, 8, 6), 256, 0, stream>>>(Wo, wopk, 512, (long)512 * 512, 1, (long)512 * 512, 0, 512);
  k_packw<<<dim3(8, 32, 6), 256, 0, stream>>>(W1, w1pk, 2048, (long)512 * 2048, 1, (long)2048 * 512, 0, 512);
  k_packw<<<dim3(32, 8, 6), 256, 0, stream>>>(W2, w2pk, 512, (long)2048 * 512, 1, (long)512 * 2048, 0, 2048);

  k_embed<<<dim3((unsigned)((NTOK * DD) / 256)), dim3(256), 0, stream>>>(code, emb, x);

  for (int l = 0; l < LL; ++l) {
    k_ln<<<dim3(NTOK / 4), 256, 0, stream>>>(x, xn, nullptr, ln1_g + l * DD, ln1_b + l * DD,
                                             nullptr, nullptr, nullptr);
    // QKV (mode 3: q-part pre-scaled by 1/8): 64x64 tiles -> 3072 waves
    k_pgemm<4><<<dim3(24 * 128), 64, 0, stream>>>(xn, wqpk + (size_t)l * 1536 * 512, nullptr, nullptr,
                                                  nullptr, qkv, (int)NTOK, 1536, 512, 3);
    k_attn<<<dim3(BB * HH * (TT / 64)), 256, 0, stream>>>(qkv, lengths, xn);
    // Wo + bias + residual -> x (fp32): 32x64 tiles -> 2048 waves (2/SIMD)
    k_pgemm<2><<<dim3(8 * 256), 64, 0, stream>>>(xn, wopk + (size_t)l * 512 * 512, x, bo + l * DD,
                                                 x, nullptr, (int)NTOK, 512, 512, 1);
    k_ln<<<dim3(NTOK / 4), 256, 0, stream>>>(x, xn, nullptr, ln2_g + l * DD, ln2_b + l * DD,
                                             nullptr, nullptr, nullptr);
    // W1 + bias + GELU -> h1 (packed bf16): 64x64 tiles -> 4096 waves
    k_pgemm<4><<<dim3(32 * 128), 64, 0, stream>>>(xn, w1pk + (size_t)l * 512 * FF4, nullptr, b1 + l * FF4,
                                                  nullptr, h1, (int)NTOK, FF4, 512, 2);
    // W2 + bias + residual -> x (fp32): K=2048, 32x64 tiles -> 2048 waves (2/SIMD)
    k_pgemm<2><<<dim3(8 * 256), 64, 0, stream>>>(h1, w2pk + (size_t)l * FF4 * 512, x, b2 + l * DD,
                                                 x, nullptr, (int)NTOK, 512, 2048, 1);
  }
  k_ln<<<dim3(NTOK / 4), 256, 0, stream>>>(x, nullptr, xf, lnf_g, lnf_b,
                                           attn_w, attn_b, scores);
  k_softw<<<dim3(BB), 256, 0, stream>>>(scores, lengths, wts);
  k_wsum<<<dim3(BB, 16), 256, 0, stream>>>(xf, wts, partial);
  k_head<<<dim3(BB), 64, 0, stream>>>(partial, head_w, head_b, out);
}

// Round 11
// 1422.043 us; speedup vs baseline: 1.2991x; 1.0093x over previous
//
#include <hip/hip_runtime.h>
#include <math.h>

#define TT 1024
#define BB 8
#define DD 512
#define HH 8
#define HSZ 64
#define LL 6
#define FF4 2048

typedef __attribute__((ext_vector_type(8))) short short8;
typedef __attribute__((ext_vector_type(4))) float floatx4;
typedef unsigned short ushort_t;
typedef unsigned int uint_t;

__device__ __forceinline__ ushort_t f2bf(float f) {
  uint_t u = __float_as_uint(f);
  u += 0x7fff + ((u >> 16) & 1);  // RNE
  return (ushort_t)(u >> 16);
}
__device__ __forceinline__ float bf2f(ushort_t h) {
  return __uint_as_float(((uint_t)h) << 16);
}

#if defined(__has_builtin)
#if __has_builtin(__builtin_amdgcn_sched_group_barrier)
#define SGB(mask, n) __builtin_amdgcn_sched_group_barrier(mask, n, 0)
#endif
#endif
#ifndef SGB
#define SGB(mask, n)
#endif

// Packed MFMA-fragment layout for a [rows x Kd] bf16 matrix:
// tile (r16=row>>4, c32=col>>5); element index =
//   ((r16*(Kd>>5)+c32)<<9) + (((col>>3)&3)*16 + (row&15))*8 + (col&7)
// A wave's fragment (16 rows x 32 cols) is one contiguous 1KB chunk,
// lane i holding bytes [i*16, i*16+16) -> one coalesced global_load_dwordx4.

// ---------------- embed + positional encoding ----------------
__global__ __launch_bounds__(256) void k_embed(const int* __restrict__ code,
                                               const float* __restrict__ emb,
                                               float* __restrict__ x) {
  int idx = blockIdx.x * 256 + threadIdx.x;  // over B*T*D
  int c = idx & (DD - 1);
  int bt = idx >> 9;
  int t = bt & (TT - 1);
  int f = c >> 4, e = c & 15;
  int vv = code[bt * 32 + f];
  int i = c >> 1;
  float freq = expf((float)(2 * i) * (-9.210340371976184f / 512.f));
  float ang = (float)t * freq;
  float pe = (c & 1) ? cosf(ang) : sinf(ang);
  x[idx] = emb[vv * 16 + e] + pe;
}

// ---------------- layernorm: fp32 in -> packed bf16 (or linear fp32 + scores) ----------------
__global__ __launch_bounds__(256) void k_ln(const float* __restrict__ x,
                                            ushort_t* __restrict__ yB,
                                            float* __restrict__ yF,
                                            const float* __restrict__ g,
                                            const float* __restrict__ b,
                                            const float* __restrict__ aw,
                                            const float* __restrict__ ab,
                                            float* __restrict__ scores) {
  int wave = threadIdx.x >> 6, lane = threadIdx.x & 63;
  int row = blockIdx.x * 4 + wave;
  const float* xr = x + (size_t)row * DD;
  float v[8];
  *(float4*)&v[0] = *(const float4*)(xr + lane * 8);
  *(float4*)&v[4] = *(const float4*)(xr + lane * 8 + 4);
  float s = 0.f;
#pragma unroll
  for (int j = 0; j < 8; ++j) s += v[j];
#pragma unroll
  for (int off = 32; off; off >>= 1) s += __shfl_down(s, off, 64);
  float mean = __shfl(s, 0, 64) * (1.f / DD);
  float qv = 0.f;
#pragma unroll
  for (int j = 0; j < 8; ++j) { float d = v[j] - mean; qv += d * d; }
#pragma unroll
  for (int off = 32; off; off >>= 1) qv += __shfl_down(qv, off, 64);
  float rs = rsqrtf(__shfl(qv, 0, 64) * (1.f / DD) + 1e-5f);
  float ov[8];
  float sdot = 0.f;
#pragma unroll
  for (int e = 0; e < 8; ++e) {
    int c = lane * 8 + e;
    ov[e] = (v[e] - mean) * rs * g[c] + b[c];
    if (scores) sdot += ov[e] * aw[c];
  }
  if (yB) {
    short8 o8;
#pragma unroll
    for (int e = 0; e < 8; ++e) o8[e] = (short)f2bf(ov[e]);
    size_t ad = (((size_t)(row >> 4) * 16 + (lane >> 2)) << 9) + ((lane & 3) * 16 + (row & 15)) * 8;
    *(short8*)(yB + ad) = o8;
  } else {
    float* yr = yF + (size_t)row * DD + lane * 8;
    *(float4*)yr = *(float4*)&ov[0];
    *(float4*)(yr + 4) = *(float4*)&ov[4];
  }
  if (scores) {
#pragma unroll
    for (int off = 32; off; off >>= 1) sdot += __shfl_down(sdot, off, 64);
    if (lane == 0) scores[row] = sdot + ab[0];
  }
}

// ---------------- fp32 weights -> packed bf16 B-operand ----------------
__global__ __launch_bounds__(256) void k_packw(const float* __restrict__ in,
                                               ushort_t* __restrict__ out,
                                               int Nin, long in_ms, int nh,
                                               long os_l, int nblk, int Kout) {
  __shared__ float t4[64][65];
  int mz = blockIdx.z;
  const float* ip = in + (size_t)mz * in_ms;
  ushort_t* op = out + (size_t)(mz / nh) * os_l;
  int nbase = (mz % nh) * nblk + blockIdx.y * 64;
  int k0 = blockIdx.x * 64;
  int cc = threadIdx.x & 63, r0 = threadIdx.x >> 6;
#pragma unroll
  for (int i = 0; i < 16; ++i) {
    int r = r0 * 16 + i;
    t4[r][cc] = ip[(size_t)(k0 + r) * Nin + (nbase - (mz % nh) * nblk) + cc];
  }
  __syncthreads();
#pragma unroll
  for (int half = 0; half < 2; ++half) {
    int c = threadIdx.x + half * 256;
    int joct = c >> 6, nl = c & 63;
    int n = nbase + nl, k = k0 + joct * 8;
    short8 v8;
#pragma unroll
    for (int e = 0; e < 8; ++e) v8[e] = (short)f2bf(t4[joct * 8 + e][nl]);
    size_t ad = (((size_t)(n >> 4) * (Kout >> 5) + (k >> 5)) << 9) + (((k >> 3) & 3) * 16 + (n & 15)) * 8;
    *(short8*)(op + ad) = v8;
  }
}

// ---------------- packed-fragment MFMA GEMM: no barriers, D-deep reg pipeline ----------------
// MT=4,D=2: 64x64 wave tile (QKV/W1), launch_bounds(64,3). MT=2,D=4: 32x64
// (Wo/W2), launch_bounds(64,2) -> 256-VGPR budget for the 4-stage ring.
// sched_group_barrier pins (MFMA x 4MT)(VMEM-read x MT+4) per substep so the
// compiler can't sink the prefetch batch into serial load-use chains.
// mode 0: outB linear bf16; mode 3: same + q-part (col<512) scaled by 0.125;
// mode 1: outF = acc+bias+resid (fp32); mode 2 (MT=4): outB packed bf16 gelu(acc+bias).
template <int MT, int D>
__global__ __launch_bounds__(64, (MT == 4) ? 3 : 2) void k_pgemm(const ushort_t* __restrict__ Apk,
                                                                 const ushort_t* __restrict__ Bpk,
                                                                 const float* __restrict__ resid,
                                                                 const float* __restrict__ bias,
                                                                 float* __restrict__ outF,
                                                                 ushort_t* __restrict__ outB,
                                                                 int M, int N, int K, int mode) {
  __shared__ ushort_t Cb[MT == 4 ? 64 * 80 : 64];
  const int lane = threadIdx.x;
  const int quad = lane >> 4, l16 = lane & 15;
  const int gx = N >> 6;
  int id = blockIdx.x;
  int bx = (id >> 3) % gx;
  int by = (id / (8 * gx)) * 8 + (id & 7);  // same-row tiles share an XCD
  const int row0 = by * (MT * 16), col0 = bx * 64;
  const int nk = K >> 5;  // multiple of D for all our shapes (16 or 64)
  const ushort_t* Ab = Apk + (((size_t)(row0 >> 4) * nk) << 9) + lane * 8;
  const ushort_t* Bb = Bpk + (((size_t)(col0 >> 4) * nk) << 9) + lane * 8;
  floatx4 acc[MT][4] = {};
  short8 af[D][MT], bf[D][4];
#pragma unroll
  for (int d = 0; d < D; ++d) {
#pragma unroll
    for (int mt = 0; mt < MT; ++mt) af[d][mt] = *(const short8*)(Ab + (((size_t)(mt * nk + d)) << 9));
#pragma unroll
    for (int nt = 0; nt < 4; ++nt) bf[d][nt] = *(const short8*)(Bb + (((size_t)(nt * nk + d)) << 9));
  }
  for (int kc = 0; kc < nk; kc += D) {
#pragma unroll
    for (int d = 0; d < D; ++d) {
#pragma unroll
      for (int mt = 0; mt < MT; ++mt)
#pragma unroll
        for (int nt = 0; nt < 4; ++nt)
          acc[mt][nt] = __builtin_amdgcn_mfma_f32_16x16x32_bf16(af[d][mt], bf[d][nt], acc[mt][nt], 0, 0, 0);
      SGB(0x008, MT * 4);  // MFMA group
      const int nxt = kc + d + D;
      if (nxt < nk) {  // wave-uniform; false only in the last kc iteration
#pragma unroll
        for (int mt = 0; mt < MT; ++mt) af[d][mt] = *(const short8*)(Ab + (((size_t)(mt * nk + nxt)) << 9));
#pragma unroll
        for (int nt = 0; nt < 4; ++nt) bf[d][nt] = *(const short8*)(Bb + (((size_t)(nt * nk + nxt)) << 9));
      }
      SGB(0x020, MT + 4);  // VMEM-read group
    }
  }

  if (MT == 4 && mode == 2) {
    // gelu(acc+bias) -> per-wave LDS -> packed bf16 (Kd = N of this GEMM)
#pragma unroll
    for (int mt = 0; mt < MT; ++mt)
#pragma unroll
      for (int nt = 0; nt < 4; ++nt) {
        floatx4 a4 = acc[mt][nt];
#pragma unroll
        for (int r = 0; r < 4; ++r) {
          float val = a4[r] + bias[col0 + nt * 16 + l16];
          val = 0.5f * val * (1.f + erff(val * 0.7071067811865475f));
          Cb[(mt * 16 + quad * 4 + r) * 80 + nt * 16 + l16] = f2bf(val);
        }
      }
#pragma unroll
    for (int mt2 = 0; mt2 < 4; ++mt2)
#pragma unroll
      for (int kt2 = 0; kt2 < 2; ++kt2) {
        short8 v8 = *(const short8*)&Cb[(mt2 * 16 + l16) * 80 + kt2 * 32 + quad * 8];
        size_t ad = ((((size_t)(row0 >> 4) + mt2) * (N >> 5) + (col0 >> 5) + kt2) << 9) + lane * 8;
        *(short8*)(outB + ad) = v8;
      }
  } else {
    const float qscale = (mode == 3 && col0 < 512) ? 0.125f : 1.0f;  // pre-scale Q for attn
#pragma unroll
    for (int mt = 0; mt < MT; ++mt)
#pragma unroll
      for (int nt = 0; nt < 4; ++nt) {
        floatx4 a4 = acc[mt][nt];
#pragma unroll
        for (int r = 0; r < 4; ++r) {
          int row = row0 + mt * 16 + quad * 4 + r;
          int col = col0 + nt * 16 + l16;
          float val = a4[r];
          if (bias) val += bias[col];
          size_t idx = (size_t)row * N + col;
          if (mode == 1) outF[idx] = val + resid[idx];
          else outB[idx] = f2bf(val * qscale);
        }
      }
  }
}

// ---------------- MFMA flash attention, fixed-max softmax ----------------
// Q pre-scaled by 1/8 in QKV epilogue; post-LN scores are O(1) so exp(s) is
// safe in fp32 without a running max. Row-sum deferred: per-lane partials
// across all K-tiles, one 4-round shuffle reduction at the end.
__global__ __launch_bounds__(256) void k_attn(const ushort_t* __restrict__ qkv,
                                              const int* __restrict__ lengths,
                                              ushort_t* __restrict__ o) {
  __shared__ ushort_t Ks[64 * 72];
  __shared__ ushort_t Vt[64 * 72];
  __shared__ ushort_t Ps[4][16 * 72];  // stride 72: 2-way banks only (m136-free)
  const int tid = threadIdx.x;
  const int w = tid >> 6, lane = tid & 63;
  const int quad = lane >> 4, l16 = lane & 15;
  const int tile = blockIdx.x & 15;
  const int bh = blockIdx.x >> 4;
  const int b = bh >> 3, h = bh & 7;
  const int len = lengths[b];
  const int tqa = tile * 64 + w * 16 + l16;
  const ushort_t* qp = qkv + ((size_t)(b * TT + tqa)) * 1536 + h * HSZ + quad * 8;
  short8 qf0 = *(const short8*)qp;
  short8 qf1 = *(const short8*)(qp + 32);
  floatx4 oacc[4] = {};
  float lsum[4] = {0.f, 0.f, 0.f, 0.f};
  const int skey = tid >> 2, sseg = (tid & 3) << 4;
  const int vkp = (tid & 31) << 1, vds = (tid >> 5) << 3;
  const int nkt = (len + 63) >> 6;
  for (int kt = 0; kt < nkt; ++kt) {
    const int s0 = kt * 64;
    __syncthreads();
    {
      const ushort_t* kp = qkv + ((size_t)(b * TT + s0 + skey)) * 1536 + 512 + h * HSZ + sseg;
      short8 k0 = *(const short8*)kp;
      short8 k1 = *(const short8*)(kp + 8);
      *(short8*)&Ks[skey * 72 + sseg] = k0;
      *(short8*)&Ks[skey * 72 + sseg + 8] = k1;
      const ushort_t* vp0 = qkv + ((size_t)(b * TT + s0 + vkp)) * 1536 + 1024 + h * HSZ + vds;
      short8 v0 = *(const short8*)vp0;
      short8 v1 = *(const short8*)(vp0 + 1536);
#pragma unroll
      for (int i = 0; i < 8; ++i) {
        ushort2 pr;
        pr.x = (ushort_t)v0[i];
        pr.y = (ushort_t)v1[i];
        *(ushort2*)&Vt[(vds + i) * 72 + vkp] = pr;
      }
    }
    __syncthreads();
    floatx4 sacc[4] = {};
#pragma unroll
    for (int nt = 0; nt < 4; ++nt) {
      short8 kf0 = *(const short8*)&Ks[(nt * 16 + l16) * 72 + quad * 8];
      short8 kf1 = *(const short8*)&Ks[(nt * 16 + l16) * 72 + 32 + quad * 8];
      sacc[nt] = __builtin_amdgcn_mfma_f32_16x16x32_bf16(qf0, kf0, sacc[nt], 0, 0, 0);
      sacc[nt] = __builtin_amdgcn_mfma_f32_16x16x32_bf16(qf1, kf1, sacc[nt], 0, 0, 0);
    }
    // p = exp(score); mask only the tail tile (wave-uniform branch)
    float p[4][4];
    if (kt == nkt - 1) {
#pragma unroll
      for (int nt = 0; nt < 4; ++nt) {
        bool valid = (s0 + nt * 16 + l16 < len);
#pragma unroll
        for (int r = 0; r < 4; ++r) p[nt][r] = valid ? __expf(sacc[nt][r]) : 0.f;
      }
    } else {
#pragma unroll
      for (int nt = 0; nt < 4; ++nt)
#pragma unroll
        for (int r = 0; r < 4; ++r) p[nt][r] = __expf(sacc[nt][r]);
    }
#pragma unroll
    for (int r = 0; r < 4; ++r)
#pragma unroll
      for (int nt = 0; nt < 4; ++nt) {
        lsum[r] += p[nt][r];
        Ps[w][(quad * 4 + r) * 72 + nt * 16 + l16] = f2bf(p[nt][r]);
      }
    short8 pf0 = *(const short8*)&Ps[w][l16 * 72 + quad * 8];
    short8 pf1 = *(const short8*)&Ps[w][l16 * 72 + 32 + quad * 8];
#pragma unroll
    for (int nt = 0; nt < 4; ++nt) {
      short8 vf0 = *(const short8*)&Vt[(nt * 16 + l16) * 72 + quad * 8];
      short8 vf1 = *(const short8*)&Vt[(nt * 16 + l16) * 72 + 32 + quad * 8];
      oacc[nt] = __builtin_amdgcn_mfma_f32_16x16x32_bf16(pf0, vf0, oacc[nt], 0, 0, 0);
      oacc[nt] = __builtin_amdgcn_mfma_f32_16x16x32_bf16(pf1, vf1, oacc[nt], 0, 0, 0);
    }
  }
  // one deferred row-sum reduction across the 16 key-lanes
#pragma unroll
  for (int off = 1; off < 16; off <<= 1) {
#pragma unroll
    for (int r = 0; r < 4; ++r) lsum[r] += __shfl_xor(lsum[r], off, 64);
  }
  // epilogue: per-wave LDS shuffle into packed-A layout (Kd=512)
#pragma unroll
  for (int r = 0; r < 4; ++r) {
    int t = tile * 64 + w * 16 + quad * 4 + r;
    float inv = (t < len) ? 1.f / lsum[r] : 0.f;  // row mask
#pragma unroll
    for (int nt = 0; nt < 4; ++nt)
      Ps[w][(quad * 4 + r) * 72 + nt * 16 + l16] = f2bf(oacc[nt][r] * inv);
  }
  const int mtile = b * 64 + tile * 4 + w;
#pragma unroll
  for (int kt2 = 0; kt2 < 2; ++kt2) {
    short8 v8 = *(const short8*)&Ps[w][l16 * 72 + kt2 * 32 + quad * 8];
    size_t ad = (((size_t)mtile * 16 + h * 2 + kt2) << 9) + lane * 8;
    *(short8*)(o + ad) = v8;
  }
}

// ---------------- pool softmax: scores -> weights (per batch) ----------------
__global__ __launch_bounds__(256) void k_softw(const float* __restrict__ scores,
                                               const int* __restrict__ lengths,
                                               float* __restrict__ wts) {
  __shared__ float red[8];
  int tid = threadIdx.x, b = blockIdx.x;
  int len = lengths[b];
  const float* sb = scores + b * TT;
  float m = -1e30f;
  for (int t = tid; t < len; t += 256) m = fmaxf(m, sb[t]);
#pragma unroll
  for (int off = 32; off; off >>= 1) m = fmaxf(m, __shfl_down(m, off, 64));
  if ((tid & 63) == 0) red[tid >> 6] = m;
  __syncthreads();
  m = fmaxf(fmaxf(red[0], red[1]), fmaxf(red[2], red[3]));
  float ssum = 0.f;
  for (int t = tid; t < len; t += 256) ssum += __expf(sb[t] - m);
#pragma unroll
  for (int off = 32; off; off >>= 1) ssum += __shfl_down(ssum, off, 64);
  if ((tid & 63) == 0) red[4 + (tid >> 6)] = ssum;
  __syncthreads();
  float inv = 1.f / (red[4] + red[5] + red[6] + red[7]);
  for (int t = tid; t < TT; t += 256)
    wts[b * TT + t] = (t < len) ? __expf(sb[t] - m) * inv : 0.f;
}

// ---------------- weighted sum partials: grid (B, 16), 64 rows each ----------------
__global__ __launch_bounds__(256) void k_wsum(const float* __restrict__ xf,
                                              const float* __restrict__ wts,
                                              float* __restrict__ partial) {
  int b = blockIdx.x, c = blockIdx.y, tid = threadIdx.x;
  const float* xb = xf + ((size_t)b * TT + c * 64) * DD;
  const float* wb = wts + b * TT + c * 64;
  float a0 = 0.f, a1 = 0.f;
  for (int t = 0; t < 64; ++t) {
    float wv = wb[t];
    a0 += wv * xb[(size_t)t * DD + tid];
    a1 += wv * xb[(size_t)t * DD + tid + 256];
  }
  float* pp = partial + ((size_t)b * 16 + c) * DD;
  pp[tid] = a0;
  pp[tid + 256] = a1;
}

// ---------------- classification head (reduces the 16 partials) ----------------
__global__ __launch_bounds__(64) void k_head(const float* __restrict__ partial,
                                             const float* __restrict__ head_w,
                                             const float* __restrict__ head_b,
                                             float* __restrict__ out) {
  __shared__ float ssum[DD];
  int b = blockIdx.x, tid = threadIdx.x;
  for (int d = tid; d < DD; d += 64) {
    float s = 0.f;
#pragma unroll
    for (int c = 0; c < 16; ++c) s += partial[((size_t)b * 16 + c) * DD + d];
    ssum[d] = s;
  }
  __syncthreads();
  if (tid < 49) {
    float s = head_b[tid];
    for (int d = 0; d < DD; ++d) s += ssum[d] * head_w[d * 49 + tid];
    out[b * 49 + tid] = s;
  }
}

extern "C" void kernel_launch(void* const* d_in, const int* in_sizes, int n_in,
                              void* d_out, int out_size, void* d_ws, size_t ws_size,
                              hipStream_t stream) {
  const int* code = (const int*)d_in[0];
  const int* lengths = (const int*)d_in[1];
  const float* emb = (const float*)d_in[2];
  const float* Wq = (const float*)d_in[3];
  const float* Wk = (const float*)d_in[4];
  const float* Wv = (const float*)d_in[5];
  const float* Wo = (const float*)d_in[6];
  const float* bo = (const float*)d_in[7];
  const float* W1 = (const float*)d_in[8];
  const float* b1 = (const float*)d_in[9];
  const float* W2 = (const float*)d_in[10];
  const float* b2 = (const float*)d_in[11];
  const float* ln1_g = (const float*)d_in[12];
  const float* ln1_b = (const float*)d_in[13];
  const float* ln2_g = (const float*)d_in[14];
  const float* ln2_b = (const float*)d_in[15];
  const float* lnf_g = (const float*)d_in[16];
  const float* lnf_b = (const float*)d_in[17];
  const float* attn_w = (const float*)d_in[18];
  const float* attn_b = (const float*)d_in[19];
  const float* head_w = (const float*)d_in[20];
  const float* head_b = (const float*)d_in[21];
  float* out = (float*)d_out;

  const size_t NTOK = (size_t)BB * TT;  // 8192
  float* x = (float*)d_ws;                       // 8192*512 fp32
  ushort_t* xn = (ushort_t*)(x + NTOK * DD);     // 8192*512 bf16 (packed)
  ushort_t* un = xn + NTOK * DD;                 // union: qkv | h1 | xf
  ushort_t* qkv = un;                            // linear bf16
  ushort_t* h1 = un;                             // packed bf16
  float* xf = (float*)un;
  ushort_t* wqpk = un + (size_t)NTOK * FF4;      // packed 6x 1536x512
  ushort_t* wopk = wqpk + (size_t)LL * 1536 * 512;
  ushort_t* w1pk = wopk + (size_t)LL * 512 * 512;
  ushort_t* w2pk = w1pk + (size_t)LL * 512 * FF4;
  float* scores = (float*)(w2pk + (size_t)LL * FF4 * 512);  // 8192
  float* wts = scores + NTOK;                               // 8192
  float* partial = wts + NTOK;                              // 8*16*512

  // weight packing (fp32 [k][n] -> packed bf16 fragments)
  k_packw<<<dim3(8, 1, 48), 256, 0, stream>>>(Wq, wqpk,              64, (long)512 * 64, 8, (long)1536 * 512, 64, 512);
  k_packw<<<dim3(8, 1, 48), 256, 0, stream>>>(Wk, wqpk + 512 * 512,  64, (long)512 * 64, 8, (long)1536 * 512, 64, 512);
  k_packw<<<dim3(8, 1, 48), 256, 0, stream>>>(Wv, wqpk + 1024 * 512, 64, (long)512 * 64, 8, (long)1536 * 512, 64, 512);
  k_packw<<<dim3(8, 8, 6), 256, 0, stream>>>(Wo, wopk, 512, (long)512 * 512, 1, (long)512 * 512, 0, 512);
  k_packw<<<dim3(8, 32, 6), 256, 0, stream>>>(W1, w1pk, 2048, (long)512 * 2048, 1, (long)2048 * 512, 0, 512);
  k_packw<<<dim3(32, 8, 6), 256, 0, stream>>>(W2, w2pk, 512, (long)2048 * 512, 1, (long)512 * 2048, 0, 2048);

  k_embed<<<dim3((unsigned)((NTOK * DD) / 256)), dim3(256), 0, stream>>>(code, emb, x);

  for (int l = 0; l < LL; ++l) {
    k_ln<<<dim3(NTOK / 4), 256, 0, stream>>>(x, xn, nullptr, ln1_g + l * DD, ln1_b + l * DD,
                                             nullptr, nullptr, nullptr);
    // QKV (mode 3: q-part pre-scaled by 1/8): 64x64 tiles -> 3072 waves
    k_pgemm<4, 2><<<dim3(24 * 128), 64, 0, stream>>>(xn, wqpk + (size_t)l * 1536 * 512, nullptr, nullptr,
                                                     nullptr, qkv, (int)NTOK, 1536, 512, 3);
    k_attn<<<dim3(BB * HH * (TT / 64)), 256, 0, stream>>>(qkv, lengths, xn);
    // Wo + bias + residual -> x (fp32): 32x64 tiles, depth-4 ring -> 2048 waves
    k_pgemm<2, 4><<<dim3(8 * 256), 64, 0, stream>>>(xn, wopk + (size_t)l * 512 * 512, x, bo + l * DD,
                                                    x, nullptr, (int)NTOK, 512, 512, 1);
    k_ln<<<dim3(NTOK / 4), 256, 0, stream>>>(x, xn, nullptr, ln2_g + l * DD, ln2_b + l * DD,
                                             nullptr, nullptr, nullptr);
    // W1 + bias + GELU -> h1 (packed bf16): 64x64 tiles -> 4096 waves
    k_pgemm<4, 2><<<dim3(32 * 128), 64, 0, stream>>>(xn, w1pk + (size_t)l * 512 * FF4, nullptr, b1 + l * FF4,
                                                     nullptr, h1, (int)NTOK, FF4, 512, 2);
    // W2 + bias + residual -> x (fp32): K=2048, 32x64 tiles, depth-4 ring
    k_pgemm<2, 4><<<dim3(8 * 256), 64, 0, stream>>>(h1, w2pk + (size_t)l * FF4 * 512, x, b2 + l * DD,
                                                    x, nullptr, (int)NTOK, 512, 2048, 1);
  }
  k_ln<<<dim3(NTOK / 4), 256, 0, stream>>>(x, nullptr, xf, lnf_g, lnf_b,
                                           attn_w, attn_b, scores);
  k_softw<<<dim3(BB), 256, 0, stream>>>(scores, lengths, wts);
  k_wsum<<<dim3(BB, 16), 256, 0, stream>>>(xf, wts, partial);
  k_head<<<dim3(BB), 64, 0, stream>>>(partial, head_w, head_b, out);
}

// Round 12
// 1400.306 us; speedup vs baseline: 1.3193x; 1.0155x over previous
//
#include <hip/hip_runtime.h>
#include <math.h>

#define TT 1024
#define BB 8
#define DD 512
#define HH 8
#define HSZ 64
#define LL 6
#define FF4 2048

typedef __attribute__((ext_vector_type(8))) short short8;
typedef __attribute__((ext_vector_type(4))) float floatx4;
typedef unsigned short ushort_t;
typedef unsigned int uint_t;

__device__ __forceinline__ ushort_t f2bf(float f) {
  uint_t u = __float_as_uint(f);
  u += 0x7fff + ((u >> 16) & 1);  // RNE
  return (ushort_t)(u >> 16);
}
__device__ __forceinline__ float bf2f(ushort_t h) {
  return __uint_as_float(((uint_t)h) << 16);
}

#if defined(__has_builtin)
#if __has_builtin(__builtin_amdgcn_sched_group_barrier)
#define SGB(mask, n) __builtin_amdgcn_sched_group_barrier(mask, n, 0)
#endif
#endif
#ifndef SGB
#define SGB(mask, n)
#endif

// Packed MFMA-fragment layout for a [rows x Kd] bf16 matrix:
// tile (r16=row>>4, c32=col>>5); element index =
//   ((r16*(Kd>>5)+c32)<<9) + (((col>>3)&3)*16 + (row&15))*8 + (col&7)
// A wave's fragment (16 rows x 32 cols) is one contiguous 1KB chunk,
// lane i holding bytes [i*16, i*16+16) -> one coalesced global_load_dwordx4.

// ---------------- embed + positional encoding ----------------
__global__ __launch_bounds__(256) void k_embed(const int* __restrict__ code,
                                               const float* __restrict__ emb,
                                               float* __restrict__ x) {
  int idx = blockIdx.x * 256 + threadIdx.x;  // over B*T*D
  int c = idx & (DD - 1);
  int bt = idx >> 9;
  int t = bt & (TT - 1);
  int f = c >> 4, e = c & 15;
  int vv = code[bt * 32 + f];
  int i = c >> 1;
  float freq = expf((float)(2 * i) * (-9.210340371976184f / 512.f));
  float ang = (float)t * freq;
  float pe = (c & 1) ? cosf(ang) : sinf(ang);
  x[idx] = emb[vv * 16 + e] + pe;
}

// ---------------- layernorm: fp32 in -> packed bf16 (or linear fp32 + scores) ----------------
__global__ __launch_bounds__(256) void k_ln(const float* __restrict__ x,
                                            ushort_t* __restrict__ yB,
                                            float* __restrict__ yF,
                                            const float* __restrict__ g,
                                            const float* __restrict__ b,
                                            const float* __restrict__ aw,
                                            const float* __restrict__ ab,
                                            float* __restrict__ scores) {
  int wave = threadIdx.x >> 6, lane = threadIdx.x & 63;
  int row = blockIdx.x * 4 + wave;
  const float* xr = x + (size_t)row * DD;
  float v[8];
  *(float4*)&v[0] = *(const float4*)(xr + lane * 8);
  *(float4*)&v[4] = *(const float4*)(xr + lane * 8 + 4);
  float s = 0.f;
#pragma unroll
  for (int j = 0; j < 8; ++j) s += v[j];
#pragma unroll
  for (int off = 32; off; off >>= 1) s += __shfl_down(s, off, 64);
  float mean = __shfl(s, 0, 64) * (1.f / DD);
  float qv = 0.f;
#pragma unroll
  for (int j = 0; j < 8; ++j) { float d = v[j] - mean; qv += d * d; }
#pragma unroll
  for (int off = 32; off; off >>= 1) qv += __shfl_down(qv, off, 64);
  float rs = rsqrtf(__shfl(qv, 0, 64) * (1.f / DD) + 1e-5f);
  float ov[8];
  float sdot = 0.f;
#pragma unroll
  for (int e = 0; e < 8; ++e) {
    int c = lane * 8 + e;
    ov[e] = (v[e] - mean) * rs * g[c] + b[c];
    if (scores) sdot += ov[e] * aw[c];
  }
  if (yB) {
    short8 o8;
#pragma unroll
    for (int e = 0; e < 8; ++e) o8[e] = (short)f2bf(ov[e]);
    size_t ad = (((size_t)(row >> 4) * 16 + (lane >> 2)) << 9) + ((lane & 3) * 16 + (row & 15)) * 8;
    *(short8*)(yB + ad) = o8;
  } else {
    float* yr = yF + (size_t)row * DD + lane * 8;
    *(float4*)yr = *(float4*)&ov[0];
    *(float4*)(yr + 4) = *(float4*)&ov[4];
  }
  if (scores) {
#pragma unroll
    for (int off = 32; off; off >>= 1) sdot += __shfl_down(sdot, off, 64);
    if (lane == 0) scores[row] = sdot + ab[0];
  }
}

// ---------------- fp32 weights -> packed bf16 B-operand ----------------
__global__ __launch_bounds__(256) void k_packw(const float* __restrict__ in,
                                               ushort_t* __restrict__ out,
                                               int Nin, long in_ms, int nh,
                                               long os_l, int nblk, int Kout) {
  __shared__ float t4[64][65];
  int mz = blockIdx.z;
  const float* ip = in + (size_t)mz * in_ms;
  ushort_t* op = out + (size_t)(mz / nh) * os_l;
  int nbase = (mz % nh) * nblk + blockIdx.y * 64;
  int k0 = blockIdx.x * 64;
  int cc = threadIdx.x & 63, r0 = threadIdx.x >> 6;
#pragma unroll
  for (int i = 0; i < 16; ++i) {
    int r = r0 * 16 + i;
    t4[r][cc] = ip[(size_t)(k0 + r) * Nin + (nbase - (mz % nh) * nblk) + cc];
  }
  __syncthreads();
#pragma unroll
  for (int half = 0; half < 2; ++half) {
    int c = threadIdx.x + half * 256;
    int joct = c >> 6, nl = c & 63;
    int n = nbase + nl, k = k0 + joct * 8;
    short8 v8;
#pragma unroll
    for (int e = 0; e < 8; ++e) v8[e] = (short)f2bf(t4[joct * 8 + e][nl]);
    size_t ad = (((size_t)(n >> 4) * (Kout >> 5) + (k >> 5)) << 9) + (((k >> 3) & 3) * 16 + (n & 15)) * 8;
    *(short8*)(op + ad) = v8;
  }
}

// ---------------- packed-fragment MFMA GEMM: no barriers, peeled D-deep reg ring ----------------
// Main loop prefetches step kc+d+D UNCONDITIONALLY (peel: main body runs while
// kc+D<nk, then a load-free D-step tail) so the compiler can hold the ring in
// registers instead of predicating/sinking the loads (R11 post-mortem).
// MT=4,D=2: 64x64 wave tile (QKV/W1), lb(64,3). MT=2,D=4: 32x64 (Wo/W2), lb(64,2).
// mode 0: outB linear bf16; mode 3: same + q-part (col<512) scaled by 0.125;
// mode 1: outF = acc+bias+resid (fp32); mode 2 (MT=4): outB packed bf16 gelu(acc+bias).
template <int MT, int D>
__global__ __launch_bounds__(64, (MT == 4) ? 3 : 2) void k_pgemm(const ushort_t* __restrict__ Apk,
                                                                 const ushort_t* __restrict__ Bpk,
                                                                 const float* __restrict__ resid,
                                                                 const float* __restrict__ bias,
                                                                 float* __restrict__ outF,
                                                                 ushort_t* __restrict__ outB,
                                                                 int M, int N, int K, int mode) {
  __shared__ ushort_t Cb[MT == 4 ? 64 * 80 : 64];
  const int lane = threadIdx.x;
  const int quad = lane >> 4, l16 = lane & 15;
  const int gx = N >> 6;
  int id = blockIdx.x;
  int bx = (id >> 3) % gx;
  int by = (id / (8 * gx)) * 8 + (id & 7);  // same-row tiles share an XCD
  const int row0 = by * (MT * 16), col0 = bx * 64;
  const int nk = K >> 5;  // multiple of D for all our shapes (16 or 64)
  const ushort_t* Ab = Apk + (((size_t)(row0 >> 4) * nk) << 9) + lane * 8;
  const ushort_t* Bb = Bpk + (((size_t)(col0 >> 4) * nk) << 9) + lane * 8;
  floatx4 acc[MT][4] = {};
  short8 af[D][MT], bf[D][4];
#pragma unroll
  for (int d = 0; d < D; ++d) {
#pragma unroll
    for (int mt = 0; mt < MT; ++mt) af[d][mt] = *(const short8*)(Ab + (((size_t)(mt * nk + d)) << 9));
#pragma unroll
    for (int nt = 0; nt < 4; ++nt) bf[d][nt] = *(const short8*)(Bb + (((size_t)(nt * nk + d)) << 9));
  }
  int kc = 0;
  for (; kc + D < nk; kc += D) {
#pragma unroll
    for (int d = 0; d < D; ++d) {
#pragma unroll
      for (int mt = 0; mt < MT; ++mt)
#pragma unroll
        for (int nt = 0; nt < 4; ++nt)
          acc[mt][nt] = __builtin_amdgcn_mfma_f32_16x16x32_bf16(af[d][mt], bf[d][nt], acc[mt][nt], 0, 0, 0);
      SGB(0x008, MT * 4);  // MFMA group
      const int nxt = kc + d + D;  // unconditional: main body guarantees nxt < nk
#pragma unroll
      for (int mt = 0; mt < MT; ++mt) af[d][mt] = *(const short8*)(Ab + (((size_t)(mt * nk + nxt)) << 9));
#pragma unroll
      for (int nt = 0; nt < 4; ++nt) bf[d][nt] = *(const short8*)(Bb + (((size_t)(nt * nk + nxt)) << 9));
      SGB(0x020, MT + 4);  // VMEM-read group
    }
  }
  // load-free tail: the last D k-steps
#pragma unroll
  for (int d = 0; d < D; ++d)
#pragma unroll
    for (int mt = 0; mt < MT; ++mt)
#pragma unroll
      for (int nt = 0; nt < 4; ++nt)
        acc[mt][nt] = __builtin_amdgcn_mfma_f32_16x16x32_bf16(af[d][mt], bf[d][nt], acc[mt][nt], 0, 0, 0);

  if (MT == 4 && mode == 2) {
    // gelu(acc+bias) -> per-wave LDS -> packed bf16 (Kd = N of this GEMM)
#pragma unroll
    for (int mt = 0; mt < MT; ++mt)
#pragma unroll
      for (int nt = 0; nt < 4; ++nt) {
        floatx4 a4 = acc[mt][nt];
#pragma unroll
        for (int r = 0; r < 4; ++r) {
          float val = a4[r] + bias[col0 + nt * 16 + l16];
          val = 0.5f * val * (1.f + erff(val * 0.7071067811865475f));
          Cb[(mt * 16 + quad * 4 + r) * 80 + nt * 16 + l16] = f2bf(val);
        }
      }
#pragma unroll
    for (int mt2 = 0; mt2 < 4; ++mt2)
#pragma unroll
      for (int kt2 = 0; kt2 < 2; ++kt2) {
        short8 v8 = *(const short8*)&Cb[(mt2 * 16 + l16) * 80 + kt2 * 32 + quad * 8];
        size_t ad = ((((size_t)(row0 >> 4) + mt2) * (N >> 5) + (col0 >> 5) + kt2) << 9) + lane * 8;
        *(short8*)(outB + ad) = v8;
      }
  } else {
    const float qscale = (mode == 3 && col0 < 512) ? 0.125f : 1.0f;  // pre-scale Q for attn
#pragma unroll
    for (int mt = 0; mt < MT; ++mt)
#pragma unroll
      for (int nt = 0; nt < 4; ++nt) {
        floatx4 a4 = acc[mt][nt];
#pragma unroll
        for (int r = 0; r < 4; ++r) {
          int row = row0 + mt * 16 + quad * 4 + r;
          int col = col0 + nt * 16 + l16;
          float val = a4[r];
          if (bias) val += bias[col];
          size_t idx = (size_t)row * N + col;
          if (mode == 1) outF[idx] = val + resid[idx];
          else outB[idx] = f2bf(val * qscale);
        }
      }
  }
}

// ---------------- MFMA flash attention, fixed-max softmax ----------------
// Q pre-scaled by 1/8 in QKV epilogue; post-LN scores are O(1) so exp(s) is
// safe in fp32 without a running max. Row-sum deferred: per-lane partials
// across all K-tiles, one 4-round shuffle reduction at the end.
__global__ __launch_bounds__(256) void k_attn(const ushort_t* __restrict__ qkv,
                                              const int* __restrict__ lengths,
                                              ushort_t* __restrict__ o) {
  __shared__ ushort_t Ks[64 * 72];
  __shared__ ushort_t Vt[64 * 72];
  __shared__ ushort_t Ps[4][16 * 72];  // stride 72: 2-way banks only (m136-free)
  const int tid = threadIdx.x;
  const int w = tid >> 6, lane = tid & 63;
  const int quad = lane >> 4, l16 = lane & 15;
  const int tile = blockIdx.x & 15;
  const int bh = blockIdx.x >> 4;
  const int b = bh >> 3, h = bh & 7;
  const int len = lengths[b];
  const int tqa = tile * 64 + w * 16 + l16;
  const ushort_t* qp = qkv + ((size_t)(b * TT + tqa)) * 1536 + h * HSZ + quad * 8;
  short8 qf0 = *(const short8*)qp;
  short8 qf1 = *(const short8*)(qp + 32);
  floatx4 oacc[4] = {};
  float lsum[4] = {0.f, 0.f, 0.f, 0.f};
  const int skey = tid >> 2, sseg = (tid & 3) << 4;
  const int vkp = (tid & 31) << 1, vds = (tid >> 5) << 3;
  const int nkt = (len + 63) >> 6;
  for (int kt = 0; kt < nkt; ++kt) {
    const int s0 = kt * 64;
    __syncthreads();
    {
      const ushort_t* kp = qkv + ((size_t)(b * TT + s0 + skey)) * 1536 + 512 + h * HSZ + sseg;
      short8 k0 = *(const short8*)kp;
      short8 k1 = *(const short8*)(kp + 8);
      *(short8*)&Ks[skey * 72 + sseg] = k0;
      *(short8*)&Ks[skey * 72 + sseg + 8] = k1;
      const ushort_t* vp0 = qkv + ((size_t)(b * TT + s0 + vkp)) * 1536 + 1024 + h * HSZ + vds;
      short8 v0 = *(const short8*)vp0;
      short8 v1 = *(const short8*)(vp0 + 1536);
#pragma unroll
      for (int i = 0; i < 8; ++i) {
        ushort2 pr;
        pr.x = (ushort_t)v0[i];
        pr.y = (ushort_t)v1[i];
        *(ushort2*)&Vt[(vds + i) * 72 + vkp] = pr;
      }
    }
    __syncthreads();
    floatx4 sacc[4] = {};
#pragma unroll
    for (int nt = 0; nt < 4; ++nt) {
      short8 kf0 = *(const short8*)&Ks[(nt * 16 + l16) * 72 + quad * 8];
      short8 kf1 = *(const short8*)&Ks[(nt * 16 + l16) * 72 + 32 + quad * 8];
      sacc[nt] = __builtin_amdgcn_mfma_f32_16x16x32_bf16(qf0, kf0, sacc[nt], 0, 0, 0);
      sacc[nt] = __builtin_amdgcn_mfma_f32_16x16x32_bf16(qf1, kf1, sacc[nt], 0, 0, 0);
    }
    // p = exp(score); mask only the tail tile (wave-uniform branch)
    float p[4][4];
    if (kt == nkt - 1) {
#pragma unroll
      for (int nt = 0; nt < 4; ++nt) {
        bool valid = (s0 + nt * 16 + l16 < len);
#pragma unroll
        for (int r = 0; r < 4; ++r) p[nt][r] = valid ? __expf(sacc[nt][r]) : 0.f;
      }
    } else {
#pragma unroll
      for (int nt = 0; nt < 4; ++nt)
#pragma unroll
        for (int r = 0; r < 4; ++r) p[nt][r] = __expf(sacc[nt][r]);
    }
#pragma unroll
    for (int r = 0; r < 4; ++r)
#pragma unroll
      for (int nt = 0; nt < 4; ++nt) {
        lsum[r] += p[nt][r];
        Ps[w][(quad * 4 + r) * 72 + nt * 16 + l16] = f2bf(p[nt][r]);
      }
    short8 pf0 = *(const short8*)&Ps[w][l16 * 72 + quad * 8];
    short8 pf1 = *(const short8*)&Ps[w][l16 * 72 + 32 + quad * 8];
#pragma unroll
    for (int nt = 0; nt < 4; ++nt) {
      short8 vf0 = *(const short8*)&Vt[(nt * 16 + l16) * 72 + quad * 8];
      short8 vf1 = *(const short8*)&Vt[(nt * 16 + l16) * 72 + 32 + quad * 8];
      oacc[nt] = __builtin_amdgcn_mfma_f32_16x16x32_bf16(pf0, vf0, oacc[nt], 0, 0, 0);
      oacc[nt] = __builtin_amdgcn_mfma_f32_16x16x32_bf16(pf1, vf1, oacc[nt], 0, 0, 0);
    }
  }
  // one deferred row-sum reduction across the 16 key-lanes
#pragma unroll
  for (int off = 1; off < 16; off <<= 1) {
#pragma unroll
    for (int r = 0; r < 4; ++r) lsum[r] += __shfl_xor(lsum[r], off, 64);
  }
  // epilogue: per-wave LDS shuffle into packed-A layout (Kd=512)
#pragma unroll
  for (int r = 0; r < 4; ++r) {
    int t = tile * 64 + w * 16 + quad * 4 + r;
    float inv = (t < len) ? 1.f / lsum[r] : 0.f;  // row mask
#pragma unroll
    for (int nt = 0; nt < 4; ++nt)
      Ps[w][(quad * 4 + r) * 72 + nt * 16 + l16] = f2bf(oacc[nt][r] * inv);
  }
  const int mtile = b * 64 + tile * 4 + w;
#pragma unroll
  for (int kt2 = 0; kt2 < 2; ++kt2) {
    short8 v8 = *(const short8*)&Ps[w][l16 * 72 + kt2 * 32 + quad * 8];
    size_t ad = (((size_t)mtile * 16 + h * 2 + kt2) << 9) + lane * 8;
    *(short8*)(o + ad) = v8;
  }
}

// ---------------- pool softmax: scores -> weights (per batch) ----------------
__global__ __launch_bounds__(256) void k_softw(const float* __restrict__ scores,
                                               const int* __restrict__ lengths,
                                               float* __restrict__ wts) {
  __shared__ float red[8];
  int tid = threadIdx.x, b = blockIdx.x;
  int len = lengths[b];
  const float* sb = scores + b * TT;
  float m = -1e30f;
  for (int t = tid; t < len; t += 256) m = fmaxf(m, sb[t]);
#pragma unroll
  for (int off = 32; off; off >>= 1) m = fmaxf(m, __shfl_down(m, off, 64));
  if ((tid & 63) == 0) red[tid >> 6] = m;
  __syncthreads();
  m = fmaxf(fmaxf(red[0], red[1]), fmaxf(red[2], red[3]));
  float ssum = 0.f;
  for (int t = tid; t < len; t += 256) ssum += __expf(sb[t] - m);
#pragma unroll
  for (int off = 32; off; off >>= 1) ssum += __shfl_down(ssum, off, 64);
  if ((tid & 63) == 0) red[4 + (tid >> 6)] = ssum;
  __syncthreads();
  float inv = 1.f / (red[4] + red[5] + red[6] + red[7]);
  for (int t = tid; t < TT; t += 256)
    wts[b * TT + t] = (t < len) ? __expf(sb[t] - m) * inv : 0.f;
}

// ---------------- weighted sum partials: grid (B, 16), 64 rows each ----------------
__global__ __launch_bounds__(256) void k_wsum(const float* __restrict__ xf,
                                              const float* __restrict__ wts,
                                              float* __restrict__ partial) {
  int b = blockIdx.x, c = blockIdx.y, tid = threadIdx.x;
  const float* xb = xf + ((size_t)b * TT + c * 64) * DD;
  const float* wb = wts + b * TT + c * 64;
  float a0 = 0.f, a1 = 0.f;
  for (int t = 0; t < 64; ++t) {
    float wv = wb[t];
    a0 += wv * xb[(size_t)t * DD + tid];
    a1 += wv * xb[(size_t)t * DD + tid + 256];
  }
  float* pp = partial + ((size_t)b * 16 + c) * DD;
  pp[tid] = a0;
  pp[tid + 256] = a1;
}

// ---------------- classification head (reduces the 16 partials) ----------------
__global__ __launch_bounds__(64) void k_head(const float* __restrict__ partial,
                                             const float* __restrict__ head_w,
                                             const float* __restrict__ head_b,
                                             float* __restrict__ out) {
  __shared__ float ssum[DD];
  int b = blockIdx.x, tid = threadIdx.x;
  for (int d = tid; d < DD; d += 64) {
    float s = 0.f;
#pragma unroll
    for (int c = 0; c < 16; ++c) s += partial[((size_t)b * 16 + c) * DD + d];
    ssum[d] = s;
  }
  __syncthreads();
  if (tid < 49) {
    float s = head_b[tid];
    for (int d = 0; d < DD; ++d) s += ssum[d] * head_w[d * 49 + tid];
    out[b * 49 + tid] = s;
  }
}

extern "C" void kernel_launch(void* const* d_in, const int* in_sizes, int n_in,
                              void* d_out, int out_size, void* d_ws, size_t ws_size,
                              hipStream_t stream) {
  const int* code = (const int*)d_in[0];
  const int* lengths = (const int*)d_in[1];
  const float* emb = (const float*)d_in[2];
  const float* Wq = (const float*)d_in[3];
  const float* Wk = (const float*)d_in[4];
  const float* Wv = (const float*)d_in[5];
  const float* Wo = (const float*)d_in[6];
  const float* bo = (const float*)d_in[7];
  const float* W1 = (const float*)d_in[8];
  const float* b1 = (const float*)d_in[9];
  const float* W2 = (const float*)d_in[10];
  const float* b2 = (const float*)d_in[11];
  const float* ln1_g = (const float*)d_in[12];
  const float* ln1_b = (const float*)d_in[13];
  const float* ln2_g = (const float*)d_in[14];
  const float* ln2_b = (const float*)d_in[15];
  const float* lnf_g = (const float*)d_in[16];
  const float* lnf_b = (const float*)d_in[17];
  const float* attn_w = (const float*)d_in[18];
  const float* attn_b = (const float*)d_in[19];
  const float* head_w = (const float*)d_in[20];
  const float* head_b = (const float*)d_in[21];
  float* out = (float*)d_out;

  const size_t NTOK = (size_t)BB * TT;  // 8192
  float* x = (float*)d_ws;                       // 8192*512 fp32
  ushort_t* xn = (ushort_t*)(x + NTOK * DD);     // 8192*512 bf16 (packed)
  ushort_t* un = xn + NTOK * DD;                 // union: qkv | h1 | xf
  ushort_t* qkv = un;                            // linear bf16
  ushort_t* h1 = un;                             // packed bf16
  float* xf = (float*)un;
  ushort_t* wqpk = un + (size_t)NTOK * FF4;      // packed 6x 1536x512
  ushort_t* wopk = wqpk + (size_t)LL * 1536 * 512;
  ushort_t* w1pk = wopk + (size_t)LL * 512 * 512;
  ushort_t* w2pk = w1pk + (size_t)LL * 512 * FF4;
  float* scores = (float*)(w2pk + (size_t)LL * FF4 * 512);  // 8192
  float* wts = scores + NTOK;                               // 8192
  float* partial = wts + NTOK;                              // 8*16*512

  // weight packing (fp32 [k][n] -> packed bf16 fragments)
  k_packw<<<dim3(8, 1, 48), 256, 0, stream>>>(Wq, wqpk,              64, (long)512 * 64, 8, (long)1536 * 512, 64, 512);
  k_packw<<<dim3(8, 1, 48), 256, 0, stream>>>(Wk, wqpk + 512 * 512,  64, (long)512 * 64, 8, (long)1536 * 512, 64, 512);
  k_packw<<<dim3(8, 1, 48), 256, 0, stream>>>(Wv, wqpk + 1024 * 512, 64, (long)512 * 64, 8, (long)1536 * 512, 64, 512);
  k_packw<<<dim3(8, 8, 6), 256, 0, stream>>>(Wo, wopk, 512, (long)512 * 512, 1, (long)512 * 512, 0, 512);
  k_packw<<<dim3(8, 32, 6), 256, 0, stream>>>(W1, w1pk, 2048, (long)512 * 2048, 1, (long)2048 * 512, 0, 512);
  k_packw<<<dim3(32, 8, 6), 256, 0, stream>>>(W2, w2pk, 512, (long)2048 * 512, 1, (long)512 * 2048, 0, 2048);

  k_embed<<<dim3((unsigned)((NTOK * DD) / 256)), dim3(256), 0, stream>>>(code, emb, x);

  for (int l = 0; l < LL; ++l) {
    k_ln<<<dim3(NTOK / 4), 256, 0, stream>>>(x, xn, nullptr, ln1_g + l * DD, ln1_b + l * DD,
                                             nullptr, nullptr, nullptr);
    // QKV (mode 3: q-part pre-scaled by 1/8): 64x64 tiles -> 3072 waves
    k_pgemm<4, 2><<<dim3(24 * 128), 64, 0, stream>>>(xn, wqpk + (size_t)l * 1536 * 512, nullptr, nullptr,
                                                     nullptr, qkv, (int)NTOK, 1536, 512, 3);
    k_attn<<<dim3(BB * HH * (TT / 64)), 256, 0, stream>>>(qkv, lengths, xn);
    // Wo + bias + residual -> x (fp32): 32x64 tiles, peeled depth-4 ring
    k_pgemm<2, 4><<<dim3(8 * 256), 64, 0, stream>>>(xn, wopk + (size_t)l * 512 * 512, x, bo + l * DD,
                                                    x, nullptr, (int)NTOK, 512, 512, 1);
    k_ln<<<dim3(NTOK / 4), 256, 0, stream>>>(x, xn, nullptr, ln2_g + l * DD, ln2_b + l * DD,
                                             nullptr, nullptr, nullptr);
    // W1 + bias + GELU -> h1 (packed bf16): 64x64 tiles -> 4096 waves
    k_pgemm<4, 2><<<dim3(32 * 128), 64, 0, stream>>>(xn, w1pk + (size_t)l * 512 * FF4, nullptr, b1 + l * FF4,
                                                     nullptr, h1, (int)NTOK, FF4, 512, 2);
    // W2 + bias + residual -> x (fp32): K=2048, 32x64 tiles, peeled depth-4 ring
    k_pgemm<2, 4><<<dim3(8 * 256), 64, 0, stream>>>(h1, w2pk + (size_t)l * FF4 * 512, x, b2 + l * DD,
                                                    x, nullptr, (int)NTOK, 512, 2048, 1);
  }
  k_ln<<<dim3(NTOK / 4), 256, 0, stream>>>(x, nullptr, xf, lnf_g, lnf_b,
                                           attn_w, attn_b, scores);
  k_softw<<<dim3(BB), 256, 0, stream>>>(scores, lengths, wts);
  k_wsum<<<dim3(BB, 16), 256, 0, stream>>>(xf, wts, partial);
  k_head<<<dim3(BB), 64, 0, stream>>>(partial, head_w, head_b, out);
}